// Round 20
// baseline (1694.886 us; speedup 1.0000x reference)
//
#include <hip/hip_runtime.h>

#define NN 50000
#define EE 500000

typedef unsigned short u16;
typedef unsigned int u32;

__device__ __forceinline__ float4 ld4(const float* p) { return *(const float4*)p; }

// round-to-nearest-even f32 -> bf16 bits (for internal fs storage only)
__device__ __forceinline__ u16 f2bf(float f) {
  u32 u = __float_as_uint(f);
  u += 0x7FFFu + ((u >> 16) & 1u);
  return (u16)(u >> 16);
}

// w[k][h] = sum_d fc_w[k*256 + h*64 + d] * attn[h*64 + d]
__global__ void L384_wred(const float* fc_w, const float* attn_l, const float* attn_r,
                          float* w_l, float* w_r) {
  int k = threadIdx.x;
  for (int h = 0; h < 4; ++h) {
    float sl = 0.f, sr = 0.f;
    for (int d = 0; d < 64; ++d) {
      float f = fc_w[k * 256 + h * 64 + d];
      sl += f * attn_l[h * 64 + d];
      sr += f * attn_r[h * 64 + d];
    }
    w_l[k * 4 + h] = sl;
    w_r[k * 4 + h] = sr;
  }
}

// C[M,256](bf16 bits) = A[M,256] @ B[256,256]; 16 rows/block, thread = column
__global__ void L384_gemm(const float* A, const float* B, u16* C, int M) {
  __shared__ float As[16][256];
  const int t = threadIdx.x;
  const int row0 = blockIdx.x * 16;
  for (int i = t; i < 1024; i += 256) {
    int r = i >> 6;
    int k4 = (i & 63) << 2;
    int grow = row0 + r;
    float4 v = make_float4(0.f, 0.f, 0.f, 0.f);
    if (grow < M) v = ld4(A + (size_t)grow * 256 + k4);
    *(float4*)&As[r][k4] = v;
  }
  __syncthreads();
  float acc[16];
  for (int r = 0; r < 16; ++r) acc[r] = 0.f;
  for (int k4 = 0; k4 < 256; k4 += 4) {
    float b0 = B[(size_t)(k4 + 0) * 256 + t];
    float b1 = B[(size_t)(k4 + 1) * 256 + t];
    float b2 = B[(size_t)(k4 + 2) * 256 + t];
    float b3 = B[(size_t)(k4 + 3) * 256 + t];
#pragma unroll
    for (int r = 0; r < 16; ++r) {
      float4 a = *(const float4*)&As[r][k4];
      acc[r] += a.x * b0 + a.y * b1 + a.z * b2 + a.w * b3;
    }
  }
  for (int r = 0; r < 16; ++r) {
    int grow = row0 + r;
    if (grow < M) C[(size_t)grow * 256 + t] = f2bf(acc[r]);
  }
}

// el/er: out[n][h] = sum_k x[n][k] * w[k*4+h]; one wave per node
__global__ void L384_av(const float* x, const float* w, float* out) {
  const int wid = blockIdx.x * 4 + (threadIdx.x >> 6);
  const int lane = threadIdx.x & 63;
  if (wid >= NN) return;
  float4 xv = ld4(x + (size_t)wid * 256 + lane * 4);
  const float* wr = w + lane * 16;
  float4 w0 = ld4(wr), w1 = ld4(wr + 4), w2 = ld4(wr + 8), w3 = ld4(wr + 12);
  float a0 = xv.x * w0.x + xv.y * w1.x + xv.z * w2.x + xv.w * w3.x;
  float a1 = xv.x * w0.y + xv.y * w1.y + xv.z * w2.y + xv.w * w3.y;
  float a2 = xv.x * w0.z + xv.y * w1.z + xv.z * w2.z + xv.w * w3.z;
  float a3 = xv.x * w0.w + xv.y * w1.w + xv.z * w2.w + xv.w * w3.w;
  for (int off = 32; off; off >>= 1) {
    a0 += __shfl_xor(a0, off);
    a1 += __shfl_xor(a1, off);
    a2 += __shfl_xor(a2, off);
    a3 += __shfl_xor(a3, off);
  }
  if (lane == 0) {
    float* op = out + (size_t)wid * 4;
    op[0] = a0; op[1] = a1; op[2] = a2; op[3] = a3;
  }
}

__global__ void L384_zero(int* p, int n) {
  int i = blockIdx.x * 256 + threadIdx.x;
  if (i < n) p[i] = 0;
}
__global__ void L384_hist(const int* dst, int* cnt) {
  int e = blockIdx.x * 256 + threadIdx.x;
  if (e < EE) {
    int d = dst[e];
    d = ((unsigned)d < NN) ? d : 0;
    atomicAdd(&cnt[d], 1);
  }
}
__global__ void L384_scan1(const int* cnt, int* part, int* bsum) {
  __shared__ int sh[256];
  const int t = threadIdx.x;
  const int base = blockIdx.x * 1024 + t * 4;
  int v0 = (base + 0 < NN) ? cnt[base + 0] : 0;
  int v1 = (base + 1 < NN) ? cnt[base + 1] : 0;
  int v2 = (base + 2 < NN) ? cnt[base + 2] : 0;
  int v3 = (base + 3 < NN) ? cnt[base + 3] : 0;
  int s0 = v0, s1 = s0 + v1, s2 = s1 + v2, s3 = s2 + v3;
  sh[t] = s3;
  __syncthreads();
  for (int off = 1; off < 256; off <<= 1) {
    int x = (t >= off) ? sh[t - off] : 0;
    __syncthreads();
    sh[t] += x;
    __syncthreads();
  }
  int excl = (t > 0) ? sh[t - 1] : 0;
  if (base + 0 < NN) part[base + 0] = excl;
  if (base + 1 < NN) part[base + 1] = excl + s0;
  if (base + 2 < NN) part[base + 2] = excl + s1;
  if (base + 3 < NN) part[base + 3] = excl + s2;
  if (t == 255) bsum[blockIdx.x] = sh[255];
}
__global__ void L384_scan2(int* bsum, int nb, int* indptr) {
  if (threadIdx.x == 0 && blockIdx.x == 0) {
    int acc = 0;
    for (int i = 0; i < nb; ++i) {
      int c = bsum[i];
      bsum[i] = acc;
      acc += c;
    }
    indptr[NN] = acc;
  }
}
__global__ void L384_scan3(int* indptr, const int* bsum, int* cur) {
  int i = blockIdx.x * 256 + threadIdx.x;
  if (i < NN) {
    int v = indptr[i] + bsum[i >> 10];
    indptr[i] = v;
    cur[i] = v;
  }
}
__global__ void L384_fill(const int* src, const int* dst, int* cur, int* csr) {
  int e = blockIdx.x * 256 + threadIdx.x;
  if (e < EE) {
    int d = dst[e];
    d = ((unsigned)d < NN) ? d : 0;
    int pos = atomicAdd(&cur[d], 1);
    if ((unsigned)pos < EE) csr[pos] = src[e];
  }
}
// per-node insertion sort of CSR segment -> deterministic summation order
// (atomicAdd in L384_fill makes intra-node order scheduling-dependent; float
// sums in L384_agg must be bit-stable across calls for the graph tripwire)
__global__ void L384_sort(const int* indptr, int* csr) {
  int i = blockIdx.x * 256 + threadIdx.x;
  if (i >= NN) return;
  int p0 = indptr[i], p1 = indptr[i + 1];
  for (int a = p0 + 1; a < p1; ++a) {
    int v = csr[a];
    int b = a - 1;
    while (b >= p0 && csr[b] > v) {
      csr[b + 1] = csr[b];
      --b;
    }
    csr[b + 1] = v;
  }
}

// one wave per dst node: edge softmax + weighted sum of fs[src]; head-mean out
__global__ void L384_agg(const int* indptr, const int* csr, const float* el,
                         const float* er, const u16* fs, const float* bias,
                         float* aggm) {
  const int wid = blockIdx.x * 4 + (threadIdx.x >> 6);
  const int lane = threadIdx.x & 63;
  if (wid >= NN) return;
  const int p0 = indptr[wid];
  const int deg = indptr[wid + 1] - p0;
  const int h = lane >> 4;
  const int c = lane & 15;
  const float* erp = er + (size_t)wid * 4;
  float er0 = erp[0], er1 = erp[1], er2 = erp[2], er3 = erp[3];

  float m0 = -1e30f, m1 = -1e30f, m2 = -1e30f, m3 = -1e30f;
  for (int i = lane; i < deg; i += 64) {
    int s = csr[p0 + i];
    s = ((unsigned)s < NN) ? s : 0;
    const float* ep = el + (size_t)s * 4;
    float e0 = ep[0] + er0; e0 = (e0 >= 0.f) ? e0 : 0.2f * e0; m0 = fmaxf(m0, e0);
    float e1 = ep[1] + er1; e1 = (e1 >= 0.f) ? e1 : 0.2f * e1; m1 = fmaxf(m1, e1);
    float e2 = ep[2] + er2; e2 = (e2 >= 0.f) ? e2 : 0.2f * e2; m2 = fmaxf(m2, e2);
    float e3 = ep[3] + er3; e3 = (e3 >= 0.f) ? e3 : 0.2f * e3; m3 = fmaxf(m3, e3);
  }
  for (int off = 32; off; off >>= 1) {
    m0 = fmaxf(m0, __shfl_xor(m0, off));
    m1 = fmaxf(m1, __shfl_xor(m1, off));
    m2 = fmaxf(m2, __shfl_xor(m2, off));
    m3 = fmaxf(m3, __shfl_xor(m3, off));
  }
  float mh = (h == 0) ? m0 : (h == 1) ? m1 : (h == 2) ? m2 : m3;
  float erh = (h == 0) ? er0 : (h == 1) ? er1 : (h == 2) ? er2 : er3;

  float den = 0.f;
  float ax = 0.f, ay = 0.f, az = 0.f, aw = 0.f;
  for (int i = 0; i < deg; ++i) {
    int s = csr[p0 + i];
    s = ((unsigned)s < NN) ? s : 0;
    float e = el[(size_t)s * 4 + h] + erh;
    e = (e >= 0.f) ? e : 0.2f * e;
    float ex = __expf(e - mh);
    den += ex;
    uint2 q = *(const uint2*)(fs + (size_t)s * 256 + lane * 4);
    float fx = __uint_as_float(q.x << 16);
    float fy = __uint_as_float(q.x & 0xffff0000u);
    float fz = __uint_as_float(q.y << 16);
    float fw = __uint_as_float(q.y & 0xffff0000u);
    ax += ex * fx; ay += ex * fy; az += ex * fz; aw += ex * fw;
  }
  const float* bp = bias + lane * 4;
  float inv = (deg > 0) ? 1.f / den : 0.f;
  float ox = ax * inv + bp[0];
  float oy = ay * inv + bp[1];
  float oz = az * inv + bp[2];
  float ow = aw * inv + bp[3];
  for (int off = 16; off <= 32; off <<= 1) {
    ox += __shfl_xor(ox, off);
    oy += __shfl_xor(oy, off);
    oz += __shfl_xor(oz, off);
    ow += __shfl_xor(ow, off);
  }
  if (h == 0) {
    float* op = aggm + (size_t)wid * 64 + 4 * c;
    op[0] = ox * 0.25f; op[1] = oy * 0.25f; op[2] = oz * 0.25f; op[3] = ow * 0.25f;
  }
}

// z = l2norm(relu([aggm, hdst] @ Ww + Wb)) -> FLOAT32 output
__global__ void L384_head(const float* aggm, const float* hdst, const float* Ww,
                          const float* Wb, float* out) {
  __shared__ float xs[32][324];
  const int t = threadIdx.x;
  const int n0 = blockIdx.x * 32;
  const int nvalid = (NN - n0 < 32) ? (NN - n0) : 32;
  for (int i = t; i < 32 * 16; i += 256) {
    int n = i >> 4, c = i & 15;
    float4 v = (n < nvalid) ? ld4(aggm + (size_t)(n0 + n) * 64 + 4 * c)
                            : make_float4(0.f, 0.f, 0.f, 0.f);
    *(float4*)&xs[n][4 * c] = v;
  }
  for (int i = t; i < 32 * 64; i += 256) {
    int n = i >> 6, c = i & 63;
    float4 v = (n < nvalid) ? ld4(hdst + (size_t)(n0 + n) * 256 + 4 * c)
                            : make_float4(0.f, 0.f, 0.f, 0.f);
    *(float4*)&xs[n][64 + 4 * c] = v;
  }
  __syncthreads();
  const int nl = t >> 3;
  const int jg = (t & 7) << 4;
  float acc[16];
  for (int i = 0; i < 16; ++i) acc[i] = 0.f;
  for (int k = 0; k < 320; ++k) {
    float x = xs[nl][k];
    const float* wr = Ww + (size_t)k * 128 + jg;
#pragma unroll
    for (int i = 0; i < 16; ++i) acc[i] += x * wr[i];
  }
  float z[16];
  float ssq = 0.f;
  for (int i = 0; i < 16; ++i) {
    float v = fmaxf(acc[i] + Wb[jg + i], 0.f);
    z[i] = v;
    ssq += v * v;
  }
  ssq += __shfl_xor(ssq, 1);
  ssq += __shfl_xor(ssq, 2);
  ssq += __shfl_xor(ssq, 4);
  if (nl < nvalid) {
    float inv = (ssq > 0.f) ? rsqrtf(ssq) : 0.f;
    float* op = out + (size_t)(n0 + nl) * 128 + jg;
    float4 o0 = make_float4(z[0] * inv, z[1] * inv, z[2] * inv, z[3] * inv);
    float4 o1 = make_float4(z[4] * inv, z[5] * inv, z[6] * inv, z[7] * inv);
    float4 o2 = make_float4(z[8] * inv, z[9] * inv, z[10] * inv, z[11] * inv);
    float4 o3 = make_float4(z[12] * inv, z[13] * inv, z[14] * inv, z[15] * inv);
    *(float4*)(op + 0) = o0;
    *(float4*)(op + 4) = o1;
    *(float4*)(op + 8) = o2;
    *(float4*)(op + 12) = o3;
  }
}

extern "C" void kernel_launch(void* const* d_in, const int* in_sizes, int n_in,
                              void* d_out, int out_size, void* d_ws, size_t ws_size,
                              hipStream_t stream) {
  (void)in_sizes; (void)n_in; (void)out_size; (void)ws_size;
  const float* h_src_user = (const float*)d_in[0];
  const float* h_src_item = (const float*)d_in[1];
  const float* h_dst_user = (const float*)d_in[2];
  const float* h_dst_item = (const float*)d_in[3];
  const int* u2i_src = (const int*)d_in[4];
  const int* u2i_dst = (const int*)d_in[5];
  const int* i2u_src = (const int*)d_in[6];
  const int* i2u_dst = (const int*)d_in[7];
  const float* fc_w = (const float*)d_in[8];
  const float* attn_l = (const float*)d_in[9];
  const float* attn_r = (const float*)d_in[10];
  const float* gat_bias = (const float*)d_in[11];
  const float* W_w = (const float*)d_in[12];
  const float* W_b = (const float*)d_in[13];
  float* out = (float*)d_out;  // FLOAT32 output (out_size f32 elements)

  float* aggm = (float*)d_ws;                   // NN*64
  float* el_u = aggm + (size_t)NN * 64;         // NN*4
  float* el_i = el_u + (size_t)NN * 4;
  float* er_u = el_i + (size_t)NN * 4;
  float* er_i = er_u + (size_t)NN * 4;
  float* w_l = er_i + (size_t)NN * 4;           // 1024
  float* w_r = w_l + 1024;                      // 1024
  u16* fs = (u16*)(w_r + 1024);                 // NN*256 bf16 bits
  int* indptr = (int*)(fs + (size_t)NN * 256);  // NN+1 (+pad)
  int* cur = indptr + (NN + 2);                 // NN
  int* csr = cur + NN;                          // EE
  int* bsum = csr + EE;                         // 64

  // shared precompute
  L384_wred<<<1, 256, 0, stream>>>(fc_w, attn_l, attn_r, w_l, w_r);
  L384_av<<<12500, 256, 0, stream>>>(h_src_user, w_l, el_u);
  L384_av<<<12500, 256, 0, stream>>>(h_src_item, w_l, el_i);
  L384_av<<<12500, 256, 0, stream>>>(h_dst_user, w_r, er_u);
  L384_av<<<12500, 256, 0, stream>>>(h_dst_item, w_r, er_i);

  // phase A: u2i (src=user, dst=item) -> z_item (second half of out)
  L384_zero<<<196, 256, 0, stream>>>(cur, NN);
  L384_hist<<<1954, 256, 0, stream>>>(u2i_dst, cur);
  L384_scan1<<<49, 256, 0, stream>>>(cur, indptr, bsum);
  L384_scan2<<<1, 1, 0, stream>>>(bsum, 49, indptr);
  L384_scan3<<<196, 256, 0, stream>>>(indptr, bsum, cur);
  L384_fill<<<1954, 256, 0, stream>>>(u2i_src, u2i_dst, cur, csr);
  L384_sort<<<196, 256, 0, stream>>>(indptr, csr);
  L384_gemm<<<3125, 256, 0, stream>>>(h_src_user, fc_w, fs, NN);
  L384_agg<<<12500, 256, 0, stream>>>(indptr, csr, el_u, er_i, fs, gat_bias, aggm);
  L384_head<<<1563, 256, 0, stream>>>(aggm, h_dst_item, W_w, W_b, out + (size_t)NN * 128);

  // phase B: i2u (src=item, dst=user) -> z_user (first half of out)
  L384_zero<<<196, 256, 0, stream>>>(cur, NN);
  L384_hist<<<1954, 256, 0, stream>>>(i2u_dst, cur);
  L384_scan1<<<49, 256, 0, stream>>>(cur, indptr, bsum);
  L384_scan2<<<1, 1, 0, stream>>>(bsum, 49, indptr);
  L384_scan3<<<196, 256, 0, stream>>>(indptr, bsum, cur);
  L384_fill<<<1954, 256, 0, stream>>>(i2u_src, i2u_dst, cur, csr);
  L384_sort<<<196, 256, 0, stream>>>(indptr, csr);
  L384_gemm<<<3125, 256, 0, stream>>>(h_src_item, fc_w, fs, NN);
  L384_agg<<<12500, 256, 0, stream>>>(indptr, csr, el_i, er_u, fs, gat_bias, aggm);
  L384_head<<<1563, 256, 0, stream>>>(aggm, h_dst_user, W_w, W_b, out);
}

// Round 21
// 951.190 us; speedup vs baseline: 1.7819x; 1.7819x over previous
//
#include <hip/hip_runtime.h>

#define NN 50000
#define EE 500000

typedef unsigned short u16;
typedef unsigned int u32;

__device__ __forceinline__ float4 ld4(const float* p) { return *(const float4*)p; }

// round-to-nearest-even f32 -> bf16 bits (for internal fs storage only)
__device__ __forceinline__ u16 f2bf(float f) {
  u32 u = __float_as_uint(f);
  u += 0x7FFFu + ((u >> 16) & 1u);
  return (u16)(u >> 16);
}

// w[k][h] = sum_d fc_w[k*256 + h*64 + d] * attn[h*64 + d]
__global__ void L384_wred(const float* fc_w, const float* attn_l, const float* attn_r,
                          float* w_l, float* w_r) {
  int k = threadIdx.x;
  for (int h = 0; h < 4; ++h) {
    float sl = 0.f, sr = 0.f;
    for (int d = 0; d < 64; ++d) {
      float f = fc_w[k * 256 + h * 64 + d];
      sl += f * attn_l[h * 64 + d];
      sr += f * attn_r[h * 64 + d];
    }
    w_l[k * 4 + h] = sl;
    w_r[k * 4 + h] = sr;
  }
}

// C[M,256](bf16 bits) = A[M,256] @ B[256,256]; 16 rows/block, thread = column
__global__ void L384_gemm(const float* A, const float* B, u16* C, int M) {
  __shared__ float As[16][256];
  const int t = threadIdx.x;
  const int row0 = blockIdx.x * 16;
  for (int i = t; i < 1024; i += 256) {
    int r = i >> 6;
    int k4 = (i & 63) << 2;
    int grow = row0 + r;
    float4 v = make_float4(0.f, 0.f, 0.f, 0.f);
    if (grow < M) v = ld4(A + (size_t)grow * 256 + k4);
    *(float4*)&As[r][k4] = v;
  }
  __syncthreads();
  float acc[16];
  for (int r = 0; r < 16; ++r) acc[r] = 0.f;
  for (int k4 = 0; k4 < 256; k4 += 4) {
    float b0 = B[(size_t)(k4 + 0) * 256 + t];
    float b1 = B[(size_t)(k4 + 1) * 256 + t];
    float b2 = B[(size_t)(k4 + 2) * 256 + t];
    float b3 = B[(size_t)(k4 + 3) * 256 + t];
#pragma unroll
    for (int r = 0; r < 16; ++r) {
      float4 a = *(const float4*)&As[r][k4];
      acc[r] += a.x * b0 + a.y * b1 + a.z * b2 + a.w * b3;
    }
  }
  for (int r = 0; r < 16; ++r) {
    int grow = row0 + r;
    if (grow < M) C[(size_t)grow * 256 + t] = f2bf(acc[r]);
  }
}

// el/er: out[n][h] = sum_k x[n][k] * w[k*4+h]; one wave per node
__global__ void L384_av(const float* x, const float* w, float* out) {
  const int wid = blockIdx.x * 4 + (threadIdx.x >> 6);
  const int lane = threadIdx.x & 63;
  if (wid >= NN) return;
  float4 xv = ld4(x + (size_t)wid * 256 + lane * 4);
  const float* wr = w + lane * 16;
  float4 w0 = ld4(wr), w1 = ld4(wr + 4), w2 = ld4(wr + 8), w3 = ld4(wr + 12);
  float a0 = xv.x * w0.x + xv.y * w1.x + xv.z * w2.x + xv.w * w3.x;
  float a1 = xv.x * w0.y + xv.y * w1.y + xv.z * w2.y + xv.w * w3.y;
  float a2 = xv.x * w0.z + xv.y * w1.z + xv.z * w2.z + xv.w * w3.z;
  float a3 = xv.x * w0.w + xv.y * w1.w + xv.z * w2.w + xv.w * w3.w;
  for (int off = 32; off; off >>= 1) {
    a0 += __shfl_xor(a0, off);
    a1 += __shfl_xor(a1, off);
    a2 += __shfl_xor(a2, off);
    a3 += __shfl_xor(a3, off);
  }
  if (lane == 0) {
    float* op = out + (size_t)wid * 4;
    op[0] = a0; op[1] = a1; op[2] = a2; op[3] = a3;
  }
}

__global__ void L384_zero(int* p, int n) {
  int i = blockIdx.x * 256 + threadIdx.x;
  if (i < n) p[i] = 0;
}
__global__ void L384_hist(const int* dst, int* cnt) {
  int e = blockIdx.x * 256 + threadIdx.x;
  if (e < EE) {
    int d = dst[e];
    d = ((unsigned)d < NN) ? d : 0;
    atomicAdd(&cnt[d], 1);
  }
}
__global__ void L384_scan1(const int* cnt, int* part, int* bsum) {
  __shared__ int sh[256];
  const int t = threadIdx.x;
  const int base = blockIdx.x * 1024 + t * 4;
  int v0 = (base + 0 < NN) ? cnt[base + 0] : 0;
  int v1 = (base + 1 < NN) ? cnt[base + 1] : 0;
  int v2 = (base + 2 < NN) ? cnt[base + 2] : 0;
  int v3 = (base + 3 < NN) ? cnt[base + 3] : 0;
  int s0 = v0, s1 = s0 + v1, s2 = s1 + v2, s3 = s2 + v3;
  sh[t] = s3;
  __syncthreads();
  for (int off = 1; off < 256; off <<= 1) {
    int x = (t >= off) ? sh[t - off] : 0;
    __syncthreads();
    sh[t] += x;
    __syncthreads();
  }
  int excl = (t > 0) ? sh[t - 1] : 0;
  if (base + 0 < NN) part[base + 0] = excl;
  if (base + 1 < NN) part[base + 1] = excl + s0;
  if (base + 2 < NN) part[base + 2] = excl + s1;
  if (base + 3 < NN) part[base + 3] = excl + s2;
  if (t == 255) bsum[blockIdx.x] = sh[255];
}
__global__ void L384_scan2(int* bsum, int nb, int* indptr) {
  if (threadIdx.x == 0 && blockIdx.x == 0) {
    int acc = 0;
    for (int i = 0; i < nb; ++i) {
      int c = bsum[i];
      bsum[i] = acc;
      acc += c;
    }
    indptr[NN] = acc;
  }
}
__global__ void L384_scan3(int* indptr, const int* bsum, int* cur) {
  int i = blockIdx.x * 256 + threadIdx.x;
  if (i < NN) {
    int v = indptr[i] + bsum[i >> 10];
    indptr[i] = v;
    cur[i] = v;
  }
}
__global__ void L384_fill(const int* src, const int* dst, int* cur, int* csr) {
  int e = blockIdx.x * 256 + threadIdx.x;
  if (e < EE) {
    int d = dst[e];
    d = ((unsigned)d < NN) ? d : 0;
    int pos = atomicAdd(&cur[d], 1);
    if ((unsigned)pos < EE) csr[pos] = src[e];
  }
}
// per-node insertion sort of CSR segment -> deterministic summation order
__global__ void L384_sort(const int* indptr, int* csr) {
  int i = blockIdx.x * 256 + threadIdx.x;
  if (i >= NN) return;
  int p0 = indptr[i], p1 = indptr[i + 1];
  for (int a = p0 + 1; a < p1; ++a) {
    int v = csr[a];
    int b = a - 1;
    while (b >= p0 && csr[b] > v) {
      csr[b + 1] = csr[b];
      --b;
    }
    csr[b + 1] = v;
  }
}

// one wave per dst node: edge softmax + weighted sum of fs[src]; head-mean out
__global__ void L384_agg(const int* indptr, const int* csr, const float* el,
                         const float* er, const u16* fs, const float* bias,
                         float* aggm) {
  const int wid = blockIdx.x * 4 + (threadIdx.x >> 6);
  const int lane = threadIdx.x & 63;
  if (wid >= NN) return;
  const int p0 = indptr[wid];
  const int deg = indptr[wid + 1] - p0;
  const int h = lane >> 4;
  const int c = lane & 15;
  const float* erp = er + (size_t)wid * 4;
  float er0 = erp[0], er1 = erp[1], er2 = erp[2], er3 = erp[3];

  float m0 = -1e30f, m1 = -1e30f, m2 = -1e30f, m3 = -1e30f;
  for (int i = lane; i < deg; i += 64) {
    int s = csr[p0 + i];
    s = ((unsigned)s < NN) ? s : 0;
    const float* ep = el + (size_t)s * 4;
    float e0 = ep[0] + er0; e0 = (e0 >= 0.f) ? e0 : 0.2f * e0; m0 = fmaxf(m0, e0);
    float e1 = ep[1] + er1; e1 = (e1 >= 0.f) ? e1 : 0.2f * e1; m1 = fmaxf(m1, e1);
    float e2 = ep[2] + er2; e2 = (e2 >= 0.f) ? e2 : 0.2f * e2; m2 = fmaxf(m2, e2);
    float e3 = ep[3] + er3; e3 = (e3 >= 0.f) ? e3 : 0.2f * e3; m3 = fmaxf(m3, e3);
  }
  for (int off = 32; off; off >>= 1) {
    m0 = fmaxf(m0, __shfl_xor(m0, off));
    m1 = fmaxf(m1, __shfl_xor(m1, off));
    m2 = fmaxf(m2, __shfl_xor(m2, off));
    m3 = fmaxf(m3, __shfl_xor(m3, off));
  }
  float mh = (h == 0) ? m0 : (h == 1) ? m1 : (h == 2) ? m2 : m3;
  float erh = (h == 0) ? er0 : (h == 1) ? er1 : (h == 2) ? er2 : er3;

  float den = 0.f;
  float ax = 0.f, ay = 0.f, az = 0.f, aw = 0.f;
  for (int i = 0; i < deg; ++i) {
    int s = csr[p0 + i];
    s = ((unsigned)s < NN) ? s : 0;
    float e = el[(size_t)s * 4 + h] + erh;
    e = (e >= 0.f) ? e : 0.2f * e;
    float ex = __expf(e - mh);
    den += ex;
    uint2 q = *(const uint2*)(fs + (size_t)s * 256 + lane * 4);
    float fx = __uint_as_float(q.x << 16);
    float fy = __uint_as_float(q.x & 0xffff0000u);
    float fz = __uint_as_float(q.y << 16);
    float fw = __uint_as_float(q.y & 0xffff0000u);
    ax += ex * fx; ay += ex * fy; az += ex * fz; aw += ex * fw;
  }
  const float* bp = bias + lane * 4;
  float inv = (deg > 0) ? 1.f / den : 0.f;
  float ox = ax * inv + bp[0];
  float oy = ay * inv + bp[1];
  float oz = az * inv + bp[2];
  float ow = aw * inv + bp[3];
  for (int off = 16; off <= 32; off <<= 1) {
    ox += __shfl_xor(ox, off);
    oy += __shfl_xor(oy, off);
    oz += __shfl_xor(oz, off);
    ow += __shfl_xor(ow, off);
  }
  if (h == 0) {
    float* op = aggm + (size_t)wid * 64 + 4 * c;
    op[0] = ox * 0.25f; op[1] = oy * 0.25f; op[2] = oz * 0.25f; op[3] = ow * 0.25f;
  }
}

// head: z = l2norm(relu([aggm, hdst] @ Ww + Wb)) -> f32 out.
// Block = 32 rows x 128 cols; thread (col=t&127, rh=t>>7) owns 16 rows x 1 col.
// Per k-chunk of 4: coalesced Ww loads + broadcast float4 LDS reads -> ILP.
__global__ void L384_head(const float* aggm, const float* hdst, const float* Ww,
                          const float* Wb, float* out) {
  __shared__ float xs[32][324];  // stride 324: k%4==0 keeps 16B-aligned float4 reads
  __shared__ float red[2][32];
  const int t = threadIdx.x;
  const int n0 = blockIdx.x * 32;
  const int nvalid = (NN - n0 < 32) ? (NN - n0) : 32;
  for (int i = t; i < 32 * 16; i += 256) {
    int n = i >> 4, c = i & 15;
    float4 v = (n < nvalid) ? ld4(aggm + (size_t)(n0 + n) * 64 + 4 * c)
                            : make_float4(0.f, 0.f, 0.f, 0.f);
    *(float4*)&xs[n][4 * c] = v;
  }
  for (int i = t; i < 32 * 64; i += 256) {
    int n = i >> 6, c = i & 63;
    float4 v = (n < nvalid) ? ld4(hdst + (size_t)(n0 + n) * 256 + 4 * c)
                            : make_float4(0.f, 0.f, 0.f, 0.f);
    *(float4*)&xs[n][64 + 4 * c] = v;
  }
  __syncthreads();

  const int col = t & 127;
  const int rh = t >> 7;    // 0/1 -> rows rh*16 .. rh*16+15
  const int r0 = rh * 16;
  float acc[16];
#pragma unroll
  for (int i = 0; i < 16; ++i) acc[i] = 0.f;

  for (int k = 0; k < 320; k += 4) {
    float w0 = Ww[(size_t)(k + 0) * 128 + col];
    float w1 = Ww[(size_t)(k + 1) * 128 + col];
    float w2 = Ww[(size_t)(k + 2) * 128 + col];
    float w3 = Ww[(size_t)(k + 3) * 128 + col];
#pragma unroll
    for (int r = 0; r < 16; ++r) {
      float4 x = *(const float4*)&xs[r0 + r][k];
      acc[r] += x.x * w0 + x.y * w1 + x.z * w2 + x.w * w3;
    }
  }

  float wb = Wb[col];
  float z[16];
#pragma unroll
  for (int r = 0; r < 16; ++r) z[r] = fmaxf(acc[r] + wb, 0.f);

  // per-row ssq: reduce over 128 col-threads = 2 waves -> shfl + LDS combine
  float part[16];
#pragma unroll
  for (int r = 0; r < 16; ++r) part[r] = z[r] * z[r];
#pragma unroll
  for (int off = 32; off; off >>= 1) {
#pragma unroll
    for (int r = 0; r < 16; ++r) part[r] += __shfl_xor(part[r], off);
  }
  const int wv = t >> 6;          // wave id 0..3
  const int half = wv & 1;        // which half of the 128 cols
  if ((t & 63) == 0) {
#pragma unroll
    for (int r = 0; r < 16; ++r) red[half][r0 + r] = part[r];
  }
  __syncthreads();
#pragma unroll
  for (int r = 0; r < 16; ++r) {
    int row = r0 + r;
    if (row < nvalid) {
      float ssq = red[0][row] + red[1][row];
      float inv = (ssq > 0.f) ? rsqrtf(ssq) : 0.f;
      out[(size_t)(n0 + row) * 128 + col] = z[r] * inv;
    }
  }
}

extern "C" void kernel_launch(void* const* d_in, const int* in_sizes, int n_in,
                              void* d_out, int out_size, void* d_ws, size_t ws_size,
                              hipStream_t stream) {
  (void)in_sizes; (void)n_in; (void)out_size; (void)ws_size;
  const float* h_src_user = (const float*)d_in[0];
  const float* h_src_item = (const float*)d_in[1];
  const float* h_dst_user = (const float*)d_in[2];
  const float* h_dst_item = (const float*)d_in[3];
  const int* u2i_src = (const int*)d_in[4];
  const int* u2i_dst = (const int*)d_in[5];
  const int* i2u_src = (const int*)d_in[6];
  const int* i2u_dst = (const int*)d_in[7];
  const float* fc_w = (const float*)d_in[8];
  const float* attn_l = (const float*)d_in[9];
  const float* attn_r = (const float*)d_in[10];
  const float* gat_bias = (const float*)d_in[11];
  const float* W_w = (const float*)d_in[12];
  const float* W_b = (const float*)d_in[13];
  float* out = (float*)d_out;  // f32 output

  float* aggm = (float*)d_ws;                   // NN*64
  float* el_u = aggm + (size_t)NN * 64;         // NN*4
  float* el_i = el_u + (size_t)NN * 4;
  float* er_u = el_i + (size_t)NN * 4;
  float* er_i = er_u + (size_t)NN * 4;
  float* w_l = er_i + (size_t)NN * 4;           // 1024
  float* w_r = w_l + 1024;                      // 1024
  u16* fs = (u16*)(w_r + 1024);                 // NN*256 bf16 bits
  int* indptr = (int*)(fs + (size_t)NN * 256);  // NN+1 (+pad)
  int* cur = indptr + (NN + 2);                 // NN
  int* csr = cur + NN;                          // EE
  int* bsum = csr + EE;                         // 64

  // shared precompute
  L384_wred<<<1, 256, 0, stream>>>(fc_w, attn_l, attn_r, w_l, w_r);
  L384_av<<<12500, 256, 0, stream>>>(h_src_user, w_l, el_u);
  L384_av<<<12500, 256, 0, stream>>>(h_src_item, w_l, el_i);
  L384_av<<<12500, 256, 0, stream>>>(h_dst_user, w_r, er_u);
  L384_av<<<12500, 256, 0, stream>>>(h_dst_item, w_r, er_i);

  // phase A: u2i (src=user, dst=item) -> z_item (second half of out)
  L384_zero<<<196, 256, 0, stream>>>(cur, NN);
  L384_hist<<<1954, 256, 0, stream>>>(u2i_dst, cur);
  L384_scan1<<<49, 256, 0, stream>>>(cur, indptr, bsum);
  L384_scan2<<<1, 1, 0, stream>>>(bsum, 49, indptr);
  L384_scan3<<<196, 256, 0, stream>>>(indptr, bsum, cur);
  L384_fill<<<1954, 256, 0, stream>>>(u2i_src, u2i_dst, cur, csr);
  L384_sort<<<196, 256, 0, stream>>>(indptr, csr);
  L384_gemm<<<3125, 256, 0, stream>>>(h_src_user, fc_w, fs, NN);
  L384_agg<<<12500, 256, 0, stream>>>(indptr, csr, el_u, er_i, fs, gat_bias, aggm);
  L384_head<<<1563, 256, 0, stream>>>(aggm, h_dst_item, W_w, W_b, out + (size_t)NN * 128);

  // phase B: i2u (src=item, dst=user) -> z_user (first half of out)
  L384_zero<<<196, 256, 0, stream>>>(cur, NN);
  L384_hist<<<1954, 256, 0, stream>>>(i2u_dst, cur);
  L384_scan1<<<49, 256, 0, stream>>>(cur, indptr, bsum);
  L384_scan2<<<1, 1, 0, stream>>>(bsum, 49, indptr);
  L384_scan3<<<196, 256, 0, stream>>>(indptr, bsum, cur);
  L384_fill<<<1954, 256, 0, stream>>>(i2u_src, i2u_dst, cur, csr);
  L384_sort<<<196, 256, 0, stream>>>(indptr, csr);
  L384_gemm<<<3125, 256, 0, stream>>>(h_src_item, fc_w, fs, NN);
  L384_agg<<<12500, 256, 0, stream>>>(indptr, csr, el_i, er_u, fs, gat_bias, aggm);
  L384_head<<<1563, 256, 0, stream>>>(aggm, h_dst_user, W_w, W_b, out);
}

// Round 22
// 821.229 us; speedup vs baseline: 2.0638x; 1.1583x over previous
//
#include <hip/hip_runtime.h>

#define NN 50000
#define EE 500000

typedef unsigned short u16;
typedef unsigned int u32;

typedef __attribute__((ext_vector_type(8))) __bf16 bf16x8;
typedef __attribute__((ext_vector_type(4))) float f32x4;

__device__ __forceinline__ float4 ld4(const float* p) { return *(const float4*)p; }

// round-to-nearest-even f32 -> bf16 bits (internal storage / MFMA inputs)
__device__ __forceinline__ u16 f2bf(float f) {
  u32 u = __float_as_uint(f);
  u += 0x7FFFu + ((u >> 16) & 1u);
  return (u16)(u >> 16);
}

// w[k][h] = sum_d fc_w[k*256 + h*64 + d] * attn[h*64 + d]
__global__ void L384_wred(const float* fc_w, const float* attn_l, const float* attn_r,
                          float* w_l, float* w_r) {
  int k = threadIdx.x;
  for (int h = 0; h < 4; ++h) {
    float sl = 0.f, sr = 0.f;
    for (int d = 0; d < 64; ++d) {
      float f = fc_w[k * 256 + h * 64 + d];
      sl += f * attn_l[h * 64 + d];
      sr += f * attn_r[h * 64 + d];
    }
    w_l[k * 4 + h] = sl;
    w_r[k * 4 + h] = sr;
  }
}

// Bt[n][k] = bf16(fc_w[k][n])  (transposed bf16 weights for MFMA B-fragments)
__global__ void L384_bprep(const float* B, u16* Bt) {
  int n = blockIdx.x;
  int k = threadIdx.x;
  Bt[n * 256 + k] = f2bf(B[(size_t)k * 256 + n]);
}

// fs[M,256](bf16) = A[M,256](f32->bf16) @ fc_w via MFMA 16x16x32 bf16.
// Block: 16 rows, 4 waves x 64-col strips; K-loop 8 x 32.
// Frag maps: A lane l -> A[row0 + (l&15)][k0+(l>>4)*8 ..+7]
//            B lane l -> Bt[col=(l&15)+c0][k0+(l>>4)*8 ..+7]   (B^T rows)
//            D lane l reg r -> C[row0+(l>>4)*4+r][c0+(l&15)]
__global__ void L384_gemm(const float* A, const u16* Bt, u16* C, int M) {
  const int t = threadIdx.x;
  const int w = t >> 6;
  const int l = t & 63;
  const int row0 = blockIdx.x * 16;
  const int lr = l & 15;
  const int kg = l >> 4;
  f32x4 acc0 = {0.f, 0.f, 0.f, 0.f};
  f32x4 acc1 = {0.f, 0.f, 0.f, 0.f};
  f32x4 acc2 = {0.f, 0.f, 0.f, 0.f};
  f32x4 acc3 = {0.f, 0.f, 0.f, 0.f};
  const float* arow = A + (size_t)(row0 + lr) * 256 + kg * 8;
  const u16* bbase = Bt + (size_t)(w * 64 + lr) * 256 + kg * 8;
  for (int k0 = 0; k0 < 256; k0 += 32) {
    union { bf16x8 v; u16 s[8]; } af;
    float4 a0 = ld4(arow + k0);
    float4 a1 = ld4(arow + k0 + 4);
    af.s[0] = f2bf(a0.x); af.s[1] = f2bf(a0.y);
    af.s[2] = f2bf(a0.z); af.s[3] = f2bf(a0.w);
    af.s[4] = f2bf(a1.x); af.s[5] = f2bf(a1.y);
    af.s[6] = f2bf(a1.z); af.s[7] = f2bf(a1.w);
    union { bf16x8 v; uint4 q; } b0, b1, b2, b3;
    b0.q = *(const uint4*)(bbase + 0 * 16 * 256 + k0);
    b1.q = *(const uint4*)(bbase + 1 * 16 * 256 + k0);
    b2.q = *(const uint4*)(bbase + 2 * 16 * 256 + k0);
    b3.q = *(const uint4*)(bbase + 3 * 16 * 256 + k0);
    acc0 = __builtin_amdgcn_mfma_f32_16x16x32_bf16(af.v, b0.v, acc0, 0, 0, 0);
    acc1 = __builtin_amdgcn_mfma_f32_16x16x32_bf16(af.v, b1.v, acc1, 0, 0, 0);
    acc2 = __builtin_amdgcn_mfma_f32_16x16x32_bf16(af.v, b2.v, acc2, 0, 0, 0);
    acc3 = __builtin_amdgcn_mfma_f32_16x16x32_bf16(af.v, b3.v, acc3, 0, 0, 0);
  }
  u16* crow = C + (size_t)(row0 + kg * 4) * 256 + w * 64 + lr;
#pragma unroll
  for (int r = 0; r < 4; ++r) {
    u16* cp = crow + (size_t)r * 256;
    cp[0] = f2bf(acc0[r]);
    cp[16] = f2bf(acc1[r]);
    cp[32] = f2bf(acc2[r]);
    cp[48] = f2bf(acc3[r]);
  }
}

// el/er: out[n][h] = sum_k x[n][k] * w[k*4+h]; one wave per node
__global__ void L384_av(const float* x, const float* w, float* out) {
  const int wid = blockIdx.x * 4 + (threadIdx.x >> 6);
  const int lane = threadIdx.x & 63;
  if (wid >= NN) return;
  float4 xv = ld4(x + (size_t)wid * 256 + lane * 4);
  const float* wr = w + lane * 16;
  float4 w0 = ld4(wr), w1 = ld4(wr + 4), w2 = ld4(wr + 8), w3 = ld4(wr + 12);
  float a0 = xv.x * w0.x + xv.y * w1.x + xv.z * w2.x + xv.w * w3.x;
  float a1 = xv.x * w0.y + xv.y * w1.y + xv.z * w2.y + xv.w * w3.y;
  float a2 = xv.x * w0.z + xv.y * w1.z + xv.z * w2.z + xv.w * w3.z;
  float a3 = xv.x * w0.w + xv.y * w1.w + xv.z * w2.w + xv.w * w3.w;
  for (int off = 32; off; off >>= 1) {
    a0 += __shfl_xor(a0, off);
    a1 += __shfl_xor(a1, off);
    a2 += __shfl_xor(a2, off);
    a3 += __shfl_xor(a3, off);
  }
  if (lane == 0) {
    float* op = out + (size_t)wid * 4;
    op[0] = a0; op[1] = a1; op[2] = a2; op[3] = a3;
  }
}

__global__ void L384_zero(int* p, int n) {
  int i = blockIdx.x * 256 + threadIdx.x;
  if (i < n) p[i] = 0;
}
__global__ void L384_hist(const int* dst, int* cnt) {
  int e = blockIdx.x * 256 + threadIdx.x;
  if (e < EE) {
    int d = dst[e];
    d = ((unsigned)d < NN) ? d : 0;
    atomicAdd(&cnt[d], 1);
  }
}
__global__ void L384_scan1(const int* cnt, int* part, int* bsum) {
  __shared__ int sh[256];
  const int t = threadIdx.x;
  const int base = blockIdx.x * 1024 + t * 4;
  int v0 = (base + 0 < NN) ? cnt[base + 0] : 0;
  int v1 = (base + 1 < NN) ? cnt[base + 1] : 0;
  int v2 = (base + 2 < NN) ? cnt[base + 2] : 0;
  int v3 = (base + 3 < NN) ? cnt[base + 3] : 0;
  int s0 = v0, s1 = s0 + v1, s2 = s1 + v2, s3 = s2 + v3;
  sh[t] = s3;
  __syncthreads();
  for (int off = 1; off < 256; off <<= 1) {
    int x = (t >= off) ? sh[t - off] : 0;
    __syncthreads();
    sh[t] += x;
    __syncthreads();
  }
  int excl = (t > 0) ? sh[t - 1] : 0;
  if (base + 0 < NN) part[base + 0] = excl;
  if (base + 1 < NN) part[base + 1] = excl + s0;
  if (base + 2 < NN) part[base + 2] = excl + s1;
  if (base + 3 < NN) part[base + 3] = excl + s2;
  if (t == 255) bsum[blockIdx.x] = sh[255];
}
__global__ void L384_scan2(int* bsum, int nb, int* indptr) {
  if (threadIdx.x == 0 && blockIdx.x == 0) {
    int acc = 0;
    for (int i = 0; i < nb; ++i) {
      int c = bsum[i];
      bsum[i] = acc;
      acc += c;
    }
    indptr[NN] = acc;
  }
}
__global__ void L384_scan3(int* indptr, const int* bsum, int* cur) {
  int i = blockIdx.x * 256 + threadIdx.x;
  if (i < NN) {
    int v = indptr[i] + bsum[i >> 10];
    indptr[i] = v;
    cur[i] = v;
  }
}
__global__ void L384_fill(const int* src, const int* dst, int* cur, int* csr) {
  int e = blockIdx.x * 256 + threadIdx.x;
  if (e < EE) {
    int d = dst[e];
    d = ((unsigned)d < NN) ? d : 0;
    int pos = atomicAdd(&cur[d], 1);
    if ((unsigned)pos < EE) csr[pos] = src[e];
  }
}
// per-node insertion sort of CSR segment -> deterministic summation order
__global__ void L384_sort(const int* indptr, int* csr) {
  int i = blockIdx.x * 256 + threadIdx.x;
  if (i >= NN) return;
  int p0 = indptr[i], p1 = indptr[i + 1];
  for (int a = p0 + 1; a < p1; ++a) {
    int v = csr[a];
    int b = a - 1;
    while (b >= p0 && csr[b] > v) {
      csr[b + 1] = csr[b];
      --b;
    }
    csr[b + 1] = v;
  }
}

// one wave per dst node: edge softmax + weighted sum of fs[src]; head-mean out
__global__ void L384_agg(const int* indptr, const int* csr, const float* el,
                         const float* er, const u16* fs, const float* bias,
                         float* aggm) {
  const int wid = blockIdx.x * 4 + (threadIdx.x >> 6);
  const int lane = threadIdx.x & 63;
  if (wid >= NN) return;
  const int p0 = indptr[wid];
  const int deg = indptr[wid + 1] - p0;
  const int h = lane >> 4;
  const int c = lane & 15;
  const float* erp = er + (size_t)wid * 4;
  float er0 = erp[0], er1 = erp[1], er2 = erp[2], er3 = erp[3];

  float m0 = -1e30f, m1 = -1e30f, m2 = -1e30f, m3 = -1e30f;
  for (int i = lane; i < deg; i += 64) {
    int s = csr[p0 + i];
    s = ((unsigned)s < NN) ? s : 0;
    const float* ep = el + (size_t)s * 4;
    float e0 = ep[0] + er0; e0 = (e0 >= 0.f) ? e0 : 0.2f * e0; m0 = fmaxf(m0, e0);
    float e1 = ep[1] + er1; e1 = (e1 >= 0.f) ? e1 : 0.2f * e1; m1 = fmaxf(m1, e1);
    float e2 = ep[2] + er2; e2 = (e2 >= 0.f) ? e2 : 0.2f * e2; m2 = fmaxf(m2, e2);
    float e3 = ep[3] + er3; e3 = (e3 >= 0.f) ? e3 : 0.2f * e3; m3 = fmaxf(m3, e3);
  }
  for (int off = 32; off; off >>= 1) {
    m0 = fmaxf(m0, __shfl_xor(m0, off));
    m1 = fmaxf(m1, __shfl_xor(m1, off));
    m2 = fmaxf(m2, __shfl_xor(m2, off));
    m3 = fmaxf(m3, __shfl_xor(m3, off));
  }
  float mh = (h == 0) ? m0 : (h == 1) ? m1 : (h == 2) ? m2 : m3;
  float erh = (h == 0) ? er0 : (h == 1) ? er1 : (h == 2) ? er2 : er3;

  float den = 0.f;
  float ax = 0.f, ay = 0.f, az = 0.f, aw = 0.f;
  for (int i = 0; i < deg; ++i) {
    int s = csr[p0 + i];
    s = ((unsigned)s < NN) ? s : 0;
    float e = el[(size_t)s * 4 + h] + erh;
    e = (e >= 0.f) ? e : 0.2f * e;
    float ex = __expf(e - mh);
    den += ex;
    uint2 q = *(const uint2*)(fs + (size_t)s * 256 + lane * 4);
    float fx = __uint_as_float(q.x << 16);
    float fy = __uint_as_float(q.x & 0xffff0000u);
    float fz = __uint_as_float(q.y << 16);
    float fw = __uint_as_float(q.y & 0xffff0000u);
    ax += ex * fx; ay += ex * fy; az += ex * fz; aw += ex * fw;
  }
  const float* bp = bias + lane * 4;
  float inv = (deg > 0) ? 1.f / den : 0.f;
  float ox = ax * inv + bp[0];
  float oy = ay * inv + bp[1];
  float oz = az * inv + bp[2];
  float ow = aw * inv + bp[3];
  for (int off = 16; off <= 32; off <<= 1) {
    ox += __shfl_xor(ox, off);
    oy += __shfl_xor(oy, off);
    oz += __shfl_xor(oz, off);
    ow += __shfl_xor(ow, off);
  }
  if (h == 0) {
    float* op = aggm + (size_t)wid * 64 + 4 * c;
    op[0] = ox * 0.25f; op[1] = oy * 0.25f; op[2] = oz * 0.25f; op[3] = ow * 0.25f;
  }
}

// head: z = l2norm(relu([aggm, hdst] @ Ww + Wb)) -> f32 out.
__global__ void L384_head(const float* aggm, const float* hdst, const float* Ww,
                          const float* Wb, float* out) {
  __shared__ float xs[32][324];
  __shared__ float red[2][32];
  const int t = threadIdx.x;
  const int n0 = blockIdx.x * 32;
  const int nvalid = (NN - n0 < 32) ? (NN - n0) : 32;
  for (int i = t; i < 32 * 16; i += 256) {
    int n = i >> 4, c = i & 15;
    float4 v = (n < nvalid) ? ld4(aggm + (size_t)(n0 + n) * 64 + 4 * c)
                            : make_float4(0.f, 0.f, 0.f, 0.f);
    *(float4*)&xs[n][4 * c] = v;
  }
  for (int i = t; i < 32 * 64; i += 256) {
    int n = i >> 6, c = i & 63;
    float4 v = (n < nvalid) ? ld4(hdst + (size_t)(n0 + n) * 256 + 4 * c)
                            : make_float4(0.f, 0.f, 0.f, 0.f);
    *(float4*)&xs[n][64 + 4 * c] = v;
  }
  __syncthreads();

  const int col = t & 127;
  const int rh = t >> 7;
  const int r0 = rh * 16;
  float acc[16];
#pragma unroll
  for (int i = 0; i < 16; ++i) acc[i] = 0.f;

  for (int k = 0; k < 320; k += 4) {
    float w0 = Ww[(size_t)(k + 0) * 128 + col];
    float w1 = Ww[(size_t)(k + 1) * 128 + col];
    float w2 = Ww[(size_t)(k + 2) * 128 + col];
    float w3 = Ww[(size_t)(k + 3) * 128 + col];
#pragma unroll
    for (int r = 0; r < 16; ++r) {
      float4 x = *(const float4*)&xs[r0 + r][k];
      acc[r] += x.x * w0 + x.y * w1 + x.z * w2 + x.w * w3;
    }
  }

  float wb = Wb[col];
  float z[16];
#pragma unroll
  for (int r = 0; r < 16; ++r) z[r] = fmaxf(acc[r] + wb, 0.f);

  float part[16];
#pragma unroll
  for (int r = 0; r < 16; ++r) part[r] = z[r] * z[r];
#pragma unroll
  for (int off = 32; off; off >>= 1) {
#pragma unroll
    for (int r = 0; r < 16; ++r) part[r] += __shfl_xor(part[r], off);
  }
  const int wv = t >> 6;
  const int half = wv & 1;
  if ((t & 63) == 0) {
#pragma unroll
    for (int r = 0; r < 16; ++r) red[half][r0 + r] = part[r];
  }
  __syncthreads();
#pragma unroll
  for (int r = 0; r < 16; ++r) {
    int row = r0 + r;
    if (row < nvalid) {
      float ssq = red[0][row] + red[1][row];
      float inv = (ssq > 0.f) ? rsqrtf(ssq) : 0.f;
      out[(size_t)(n0 + row) * 128 + col] = z[r] * inv;
    }
  }
}

extern "C" void kernel_launch(void* const* d_in, const int* in_sizes, int n_in,
                              void* d_out, int out_size, void* d_ws, size_t ws_size,
                              hipStream_t stream) {
  (void)in_sizes; (void)n_in; (void)out_size; (void)ws_size;
  const float* h_src_user = (const float*)d_in[0];
  const float* h_src_item = (const float*)d_in[1];
  const float* h_dst_user = (const float*)d_in[2];
  const float* h_dst_item = (const float*)d_in[3];
  const int* u2i_src = (const int*)d_in[4];
  const int* u2i_dst = (const int*)d_in[5];
  const int* i2u_src = (const int*)d_in[6];
  const int* i2u_dst = (const int*)d_in[7];
  const float* fc_w = (const float*)d_in[8];
  const float* attn_l = (const float*)d_in[9];
  const float* attn_r = (const float*)d_in[10];
  const float* gat_bias = (const float*)d_in[11];
  const float* W_w = (const float*)d_in[12];
  const float* W_b = (const float*)d_in[13];
  float* out = (float*)d_out;  // f32 output

  float* aggm = (float*)d_ws;                   // NN*64
  float* el_u = aggm + (size_t)NN * 64;         // NN*4
  float* el_i = el_u + (size_t)NN * 4;
  float* er_u = el_i + (size_t)NN * 4;
  float* er_i = er_u + (size_t)NN * 4;
  float* w_l = er_i + (size_t)NN * 4;           // 1024
  float* w_r = w_l + 1024;                      // 1024
  u16* fs = (u16*)(w_r + 1024);                 // NN*256 bf16 bits
  int* indptr = (int*)(fs + (size_t)NN * 256);  // NN+1 (padded to NN+4 for align)
  int* cur = indptr + (NN + 4);                 // NN
  int* csr = cur + NN;                          // EE
  int* bsum = csr + EE;                         // 64
  u16* Bt = (u16*)(bsum + 64);                  // 256*256 bf16 (fc_w transposed)

  // shared precompute
  L384_wred<<<1, 256, 0, stream>>>(fc_w, attn_l, attn_r, w_l, w_r);
  L384_bprep<<<256, 256, 0, stream>>>(fc_w, Bt);
  L384_av<<<12500, 256, 0, stream>>>(h_src_user, w_l, el_u);
  L384_av<<<12500, 256, 0, stream>>>(h_src_item, w_l, el_i);
  L384_av<<<12500, 256, 0, stream>>>(h_dst_user, w_r, er_u);
  L384_av<<<12500, 256, 0, stream>>>(h_dst_item, w_r, er_i);

  // phase A: u2i (src=user, dst=item) -> z_item (second half of out)
  L384_zero<<<196, 256, 0, stream>>>(cur, NN);
  L384_hist<<<1954, 256, 0, stream>>>(u2i_dst, cur);
  L384_scan1<<<49, 256, 0, stream>>>(cur, indptr, bsum);
  L384_scan2<<<1, 1, 0, stream>>>(bsum, 49, indptr);
  L384_scan3<<<196, 256, 0, stream>>>(indptr, bsum, cur);
  L384_fill<<<1954, 256, 0, stream>>>(u2i_src, u2i_dst, cur, csr);
  L384_sort<<<196, 256, 0, stream>>>(indptr, csr);
  L384_gemm<<<3125, 256, 0, stream>>>(h_src_user, Bt, fs, NN);
  L384_agg<<<12500, 256, 0, stream>>>(indptr, csr, el_u, er_i, fs, gat_bias, aggm);
  L384_head<<<1563, 256, 0, stream>>>(aggm, h_dst_item, W_w, W_b, out + (size_t)NN * 128);

  // phase B: i2u (src=item, dst=user) -> z_user (first half of out)
  L384_zero<<<196, 256, 0, stream>>>(cur, NN);
  L384_hist<<<1954, 256, 0, stream>>>(i2u_dst, cur);
  L384_scan1<<<49, 256, 0, stream>>>(cur, indptr, bsum);
  L384_scan2<<<1, 1, 0, stream>>>(bsum, 49, indptr);
  L384_scan3<<<196, 256, 0, stream>>>(indptr, bsum, cur);
  L384_fill<<<1954, 256, 0, stream>>>(i2u_src, i2u_dst, cur, csr);
  L384_sort<<<196, 256, 0, stream>>>(indptr, csr);
  L384_gemm<<<3125, 256, 0, stream>>>(h_src_item, Bt, fs, NN);
  L384_agg<<<12500, 256, 0, stream>>>(indptr, csr, el_i, er_u, fs, gat_bias, aggm);
  L384_head<<<1563, 256, 0, stream>>>(aggm, h_dst_user, W_w, W_b, out);
}

// Round 23
// 725.853 us; speedup vs baseline: 2.3350x; 1.1314x over previous
//
#include <hip/hip_runtime.h>

#define NN 50000
#define EE 500000

typedef unsigned short u16;
typedef unsigned int u32;

typedef __attribute__((ext_vector_type(8))) __bf16 bf16x8;
typedef __attribute__((ext_vector_type(4))) float f32x4;

__device__ __forceinline__ float4 ld4(const float* p) { return *(const float4*)p; }

// round-to-nearest-even f32 -> bf16 bits (internal storage / MFMA inputs)
__device__ __forceinline__ u16 f2bf(float f) {
  u32 u = __float_as_uint(f);
  u += 0x7FFFu + ((u >> 16) & 1u);
  return (u16)(u >> 16);
}

// w[k][h] = sum_d fc_w[k*256 + h*64 + d] * attn[h*64 + d]
__global__ void L384_wred(const float* fc_w, const float* attn_l, const float* attn_r,
                          float* w_l, float* w_r) {
  int k = threadIdx.x;
  for (int h = 0; h < 4; ++h) {
    float sl = 0.f, sr = 0.f;
    for (int d = 0; d < 64; ++d) {
      float f = fc_w[k * 256 + h * 64 + d];
      sl += f * attn_l[h * 64 + d];
      sr += f * attn_r[h * 64 + d];
    }
    w_l[k * 4 + h] = sl;
    w_r[k * 4 + h] = sr;
  }
}

// Bt[n][k] = bf16(fc_w[k][n])
__global__ void L384_bprep(const float* B, u16* Bt) {
  int n = blockIdx.x;
  int k = threadIdx.x;
  Bt[n * 256 + k] = f2bf(B[(size_t)k * 256 + n]);
}

// Wt[n][k] = bf16(Ww[k][n]), n in [0,128), k in [0,320)
__global__ void L384_wprep(const float* Ww, u16* Wt) {
  int n = blockIdx.x;
  for (int k = threadIdx.x; k < 320; k += 256)
    Wt[(size_t)n * 320 + k] = f2bf(Ww[(size_t)k * 128 + n]);
}

// X[n][64+c] = bf16(hdst[n][c]); 4 rows/block, lane handles 4 cols
__global__ void L384_xprep(const float* hdst, u16* X) {
  const int row = blockIdx.x * 4 + (threadIdx.x >> 6);
  const int lane = threadIdx.x & 63;
  if (row >= NN) return;
  float4 v = ld4(hdst + (size_t)row * 256 + lane * 4);
  u32 p01 = (u32)f2bf(v.x) | ((u32)f2bf(v.y) << 16);
  u32 p23 = (u32)f2bf(v.z) | ((u32)f2bf(v.w) << 16);
  *(uint2*)(X + (size_t)row * 320 + 64 + lane * 4) = make_uint2(p01, p23);
}

// fs[M,256](bf16) = A[M,256](f32->bf16) @ fc_w via MFMA 16x16x32 bf16.
__global__ void L384_gemm(const float* A, const u16* Bt, u16* C, int M) {
  const int t = threadIdx.x;
  const int w = t >> 6;
  const int l = t & 63;
  const int row0 = blockIdx.x * 16;
  const int lr = l & 15;
  const int kg = l >> 4;
  f32x4 acc0 = {0.f, 0.f, 0.f, 0.f};
  f32x4 acc1 = {0.f, 0.f, 0.f, 0.f};
  f32x4 acc2 = {0.f, 0.f, 0.f, 0.f};
  f32x4 acc3 = {0.f, 0.f, 0.f, 0.f};
  const float* arow = A + (size_t)(row0 + lr) * 256 + kg * 8;
  const u16* bbase = Bt + (size_t)(w * 64 + lr) * 256 + kg * 8;
  for (int k0 = 0; k0 < 256; k0 += 32) {
    union { bf16x8 v; u16 s[8]; } af;
    float4 a0 = ld4(arow + k0);
    float4 a1 = ld4(arow + k0 + 4);
    af.s[0] = f2bf(a0.x); af.s[1] = f2bf(a0.y);
    af.s[2] = f2bf(a0.z); af.s[3] = f2bf(a0.w);
    af.s[4] = f2bf(a1.x); af.s[5] = f2bf(a1.y);
    af.s[6] = f2bf(a1.z); af.s[7] = f2bf(a1.w);
    union { bf16x8 v; uint4 q; } b0, b1, b2, b3;
    b0.q = *(const uint4*)(bbase + 0 * 16 * 256 + k0);
    b1.q = *(const uint4*)(bbase + 1 * 16 * 256 + k0);
    b2.q = *(const uint4*)(bbase + 2 * 16 * 256 + k0);
    b3.q = *(const uint4*)(bbase + 3 * 16 * 256 + k0);
    acc0 = __builtin_amdgcn_mfma_f32_16x16x32_bf16(af.v, b0.v, acc0, 0, 0, 0);
    acc1 = __builtin_amdgcn_mfma_f32_16x16x32_bf16(af.v, b1.v, acc1, 0, 0, 0);
    acc2 = __builtin_amdgcn_mfma_f32_16x16x32_bf16(af.v, b2.v, acc2, 0, 0, 0);
    acc3 = __builtin_amdgcn_mfma_f32_16x16x32_bf16(af.v, b3.v, acc3, 0, 0, 0);
  }
  u16* crow = C + (size_t)(row0 + kg * 4) * 256 + w * 64 + lr;
#pragma unroll
  for (int r = 0; r < 4; ++r) {
    u16* cp = crow + (size_t)r * 256;
    cp[0] = f2bf(acc0[r]);
    cp[16] = f2bf(acc1[r]);
    cp[32] = f2bf(acc2[r]);
    cp[48] = f2bf(acc3[r]);
  }
}

// el/er: out[n][h] = sum_k x[n][k] * w[k*4+h]; one wave per node
__global__ void L384_av(const float* x, const float* w, float* out) {
  const int wid = blockIdx.x * 4 + (threadIdx.x >> 6);
  const int lane = threadIdx.x & 63;
  if (wid >= NN) return;
  float4 xv = ld4(x + (size_t)wid * 256 + lane * 4);
  const float* wr = w + lane * 16;
  float4 w0 = ld4(wr), w1 = ld4(wr + 4), w2 = ld4(wr + 8), w3 = ld4(wr + 12);
  float a0 = xv.x * w0.x + xv.y * w1.x + xv.z * w2.x + xv.w * w3.x;
  float a1 = xv.x * w0.y + xv.y * w1.y + xv.z * w2.y + xv.w * w3.y;
  float a2 = xv.x * w0.z + xv.y * w1.z + xv.z * w2.z + xv.w * w3.z;
  float a3 = xv.x * w0.w + xv.y * w1.w + xv.z * w2.w + xv.w * w3.w;
  for (int off = 32; off; off >>= 1) {
    a0 += __shfl_xor(a0, off);
    a1 += __shfl_xor(a1, off);
    a2 += __shfl_xor(a2, off);
    a3 += __shfl_xor(a3, off);
  }
  if (lane == 0) {
    float* op = out + (size_t)wid * 4;
    op[0] = a0; op[1] = a1; op[2] = a2; op[3] = a3;
  }
}

__global__ void L384_zero(int* p, int n) {
  int i = blockIdx.x * 256 + threadIdx.x;
  if (i < n) p[i] = 0;
}
__global__ void L384_hist(const int* dst, int* cnt) {
  int e = blockIdx.x * 256 + threadIdx.x;
  if (e < EE) {
    int d = dst[e];
    d = ((unsigned)d < NN) ? d : 0;
    atomicAdd(&cnt[d], 1);
  }
}
__global__ void L384_scan1(const int* cnt, int* part, int* bsum) {
  __shared__ int sh[256];
  const int t = threadIdx.x;
  const int base = blockIdx.x * 1024 + t * 4;
  int v0 = (base + 0 < NN) ? cnt[base + 0] : 0;
  int v1 = (base + 1 < NN) ? cnt[base + 1] : 0;
  int v2 = (base + 2 < NN) ? cnt[base + 2] : 0;
  int v3 = (base + 3 < NN) ? cnt[base + 3] : 0;
  int s0 = v0, s1 = s0 + v1, s2 = s1 + v2, s3 = s2 + v3;
  sh[t] = s3;
  __syncthreads();
  for (int off = 1; off < 256; off <<= 1) {
    int x = (t >= off) ? sh[t - off] : 0;
    __syncthreads();
    sh[t] += x;
    __syncthreads();
  }
  int excl = (t > 0) ? sh[t - 1] : 0;
  if (base + 0 < NN) part[base + 0] = excl;
  if (base + 1 < NN) part[base + 1] = excl + s0;
  if (base + 2 < NN) part[base + 2] = excl + s1;
  if (base + 3 < NN) part[base + 3] = excl + s2;
  if (t == 255) bsum[blockIdx.x] = sh[255];
}
__global__ void L384_scan2(int* bsum, int nb, int* indptr) {
  if (threadIdx.x == 0 && blockIdx.x == 0) {
    int acc = 0;
    for (int i = 0; i < nb; ++i) {
      int c = bsum[i];
      bsum[i] = acc;
      acc += c;
    }
    indptr[NN] = acc;
  }
}
__global__ void L384_scan3(int* indptr, const int* bsum, int* cur) {
  int i = blockIdx.x * 256 + threadIdx.x;
  if (i < NN) {
    int v = indptr[i] + bsum[i >> 10];
    indptr[i] = v;
    cur[i] = v;
  }
}
__global__ void L384_fill(const int* src, const int* dst, int* cur, int* csr) {
  int e = blockIdx.x * 256 + threadIdx.x;
  if (e < EE) {
    int d = dst[e];
    d = ((unsigned)d < NN) ? d : 0;
    int pos = atomicAdd(&cur[d], 1);
    if ((unsigned)pos < EE) csr[pos] = src[e];
  }
}
// per-node insertion sort of CSR segment -> deterministic summation order
__global__ void L384_sort(const int* indptr, int* csr) {
  int i = blockIdx.x * 256 + threadIdx.x;
  if (i >= NN) return;
  int p0 = indptr[i], p1 = indptr[i + 1];
  for (int a = p0 + 1; a < p1; ++a) {
    int v = csr[a];
    int b = a - 1;
    while (b >= p0 && csr[b] > v) {
      csr[b + 1] = csr[b];
      --b;
    }
    csr[b + 1] = v;
  }
}

// one wave per dst node: edge softmax + weighted sum of fs[src];
// head-mean (+bias) written as bf16 into X[:,0:64]
__global__ void L384_agg(const int* indptr, const int* csr, const float* el,
                         const float* er, const u16* fs, const float* bias,
                         u16* X) {
  const int wid = blockIdx.x * 4 + (threadIdx.x >> 6);
  const int lane = threadIdx.x & 63;
  if (wid >= NN) return;
  const int p0 = indptr[wid];
  const int deg = indptr[wid + 1] - p0;
  const int h = lane >> 4;
  const int c = lane & 15;
  const float* erp = er + (size_t)wid * 4;
  float er0 = erp[0], er1 = erp[1], er2 = erp[2], er3 = erp[3];

  float m0 = -1e30f, m1 = -1e30f, m2 = -1e30f, m3 = -1e30f;
  for (int i = lane; i < deg; i += 64) {
    int s = csr[p0 + i];
    s = ((unsigned)s < NN) ? s : 0;
    const float* ep = el + (size_t)s * 4;
    float e0 = ep[0] + er0; e0 = (e0 >= 0.f) ? e0 : 0.2f * e0; m0 = fmaxf(m0, e0);
    float e1 = ep[1] + er1; e1 = (e1 >= 0.f) ? e1 : 0.2f * e1; m1 = fmaxf(m1, e1);
    float e2 = ep[2] + er2; e2 = (e2 >= 0.f) ? e2 : 0.2f * e2; m2 = fmaxf(m2, e2);
    float e3 = ep[3] + er3; e3 = (e3 >= 0.f) ? e3 : 0.2f * e3; m3 = fmaxf(m3, e3);
  }
  for (int off = 32; off; off >>= 1) {
    m0 = fmaxf(m0, __shfl_xor(m0, off));
    m1 = fmaxf(m1, __shfl_xor(m1, off));
    m2 = fmaxf(m2, __shfl_xor(m2, off));
    m3 = fmaxf(m3, __shfl_xor(m3, off));
  }
  float mh = (h == 0) ? m0 : (h == 1) ? m1 : (h == 2) ? m2 : m3;
  float erh = (h == 0) ? er0 : (h == 1) ? er1 : (h == 2) ? er2 : er3;

  float den = 0.f;
  float ax = 0.f, ay = 0.f, az = 0.f, aw = 0.f;
  for (int i = 0; i < deg; ++i) {
    int s = csr[p0 + i];
    s = ((unsigned)s < NN) ? s : 0;
    float e = el[(size_t)s * 4 + h] + erh;
    e = (e >= 0.f) ? e : 0.2f * e;
    float ex = __expf(e - mh);
    den += ex;
    uint2 q = *(const uint2*)(fs + (size_t)s * 256 + lane * 4);
    float fx = __uint_as_float(q.x << 16);
    float fy = __uint_as_float(q.x & 0xffff0000u);
    float fz = __uint_as_float(q.y << 16);
    float fw = __uint_as_float(q.y & 0xffff0000u);
    ax += ex * fx; ay += ex * fy; az += ex * fz; aw += ex * fw;
  }
  const float* bp = bias + lane * 4;
  float inv = (deg > 0) ? 1.f / den : 0.f;
  float ox = ax * inv + bp[0];
  float oy = ay * inv + bp[1];
  float oz = az * inv + bp[2];
  float ow = aw * inv + bp[3];
  for (int off = 16; off <= 32; off <<= 1) {
    ox += __shfl_xor(ox, off);
    oy += __shfl_xor(oy, off);
    oz += __shfl_xor(oz, off);
    ow += __shfl_xor(ow, off);
  }
  if (h == 0) {
    u32 p01 = (u32)f2bf(ox * 0.25f) | ((u32)f2bf(oy * 0.25f) << 16);
    u32 p23 = (u32)f2bf(oz * 0.25f) | ((u32)f2bf(ow * 0.25f) << 16);
    *(uint2*)(X + (size_t)wid * 320 + 4 * c) = make_uint2(p01, p23);
  }
}

// head via MFMA: out[r][c] = l2norm_row(relu(X @ Ww + Wb)); X bf16 [NN][320].
// Block: 16 rows, 4 waves x 32-col strips (2 tiles each); K = 320 = 10 steps.
__global__ void L384_headm(const u16* X, const u16* Wt, const float* Wb, float* out) {
  __shared__ float red[4][16];
  const int t = threadIdx.x;
  const int w = t >> 6;
  const int l = t & 63;
  const int row0 = blockIdx.x * 16;
  const int lr = l & 15;
  const int kg = l >> 4;
  f32x4 acc0 = {0.f, 0.f, 0.f, 0.f};
  f32x4 acc1 = {0.f, 0.f, 0.f, 0.f};
  const u16* arow = X + (size_t)(row0 + lr) * 320 + kg * 8;
  const u16* b0row = Wt + (size_t)(w * 32 + lr) * 320 + kg * 8;
  const u16* b1row = Wt + (size_t)(w * 32 + 16 + lr) * 320 + kg * 8;
  for (int k0 = 0; k0 < 320; k0 += 32) {
    union { bf16x8 v; uint4 q; } af, b0, b1;
    af.q = *(const uint4*)(arow + k0);
    b0.q = *(const uint4*)(b0row + k0);
    b1.q = *(const uint4*)(b1row + k0);
    acc0 = __builtin_amdgcn_mfma_f32_16x16x32_bf16(af.v, b0.v, acc0, 0, 0, 0);
    acc1 = __builtin_amdgcn_mfma_f32_16x16x32_bf16(af.v, b1.v, acc1, 0, 0, 0);
  }
  const int col0 = w * 32 + lr;
  const int col1 = col0 + 16;
  float wb0 = Wb[col0], wb1 = Wb[col1];
  float z0[4], z1[4], pssq[4];
#pragma unroll
  for (int r = 0; r < 4; ++r) {
    z0[r] = fmaxf(acc0[r] + wb0, 0.f);
    z1[r] = fmaxf(acc1[r] + wb1, 0.f);
    pssq[r] = z0[r] * z0[r] + z1[r] * z1[r];
  }
#pragma unroll
  for (int off = 8; off; off >>= 1) {
#pragma unroll
    for (int r = 0; r < 4; ++r) pssq[r] += __shfl_xor(pssq[r], off);
  }
  if (lr == 0) {
#pragma unroll
    for (int r = 0; r < 4; ++r) red[w][kg * 4 + r] = pssq[r];
  }
  __syncthreads();
#pragma unroll
  for (int r = 0; r < 4; ++r) {
    int row = kg * 4 + r;
    float ssq = red[0][row] + red[1][row] + red[2][row] + red[3][row];
    float inv = (ssq > 0.f) ? rsqrtf(ssq) : 0.f;
    float* op = out + (size_t)(row0 + row) * 128;
    op[col0] = z0[r] * inv;
    op[col1] = z1[r] * inv;
  }
}

extern "C" void kernel_launch(void* const* d_in, const int* in_sizes, int n_in,
                              void* d_out, int out_size, void* d_ws, size_t ws_size,
                              hipStream_t stream) {
  (void)in_sizes; (void)n_in; (void)out_size; (void)ws_size;
  const float* h_src_user = (const float*)d_in[0];
  const float* h_src_item = (const float*)d_in[1];
  const float* h_dst_user = (const float*)d_in[2];
  const float* h_dst_item = (const float*)d_in[3];
  const int* u2i_src = (const int*)d_in[4];
  const int* u2i_dst = (const int*)d_in[5];
  const int* i2u_src = (const int*)d_in[6];
  const int* i2u_dst = (const int*)d_in[7];
  const float* fc_w = (const float*)d_in[8];
  const float* attn_l = (const float*)d_in[9];
  const float* attn_r = (const float*)d_in[10];
  const float* gat_bias = (const float*)d_in[11];
  const float* W_w = (const float*)d_in[12];
  const float* W_b = (const float*)d_in[13];
  float* out = (float*)d_out;  // f32 output

  float* el_u = (float*)d_ws;                   // NN*4
  float* el_i = el_u + (size_t)NN * 4;
  float* er_u = el_i + (size_t)NN * 4;
  float* er_i = er_u + (size_t)NN * 4;
  float* w_l = er_i + (size_t)NN * 4;           // 1024
  float* w_r = w_l + 1024;                      // 1024
  u16* fs = (u16*)(w_r + 1024);                 // NN*256 bf16
  u16* Xi = fs + (size_t)NN * 256;              // NN*320 bf16 (item head input)
  u16* Xu = Xi + (size_t)NN * 320;              // NN*320 bf16 (user head input)
  u16* Bt = Xu + (size_t)NN * 320;              // 256*256 bf16
  u16* Wt = Bt + 256 * 256;                     // 128*320 bf16
  int* indptr = (int*)(Wt + 128 * 320);         // NN+1 (+pad)
  int* cur = indptr + (NN + 4);                 // NN
  int* csr = cur + NN;                          // EE
  int* bsum = csr + EE;                         // 64

  // shared precompute
  L384_wred<<<1, 256, 0, stream>>>(fc_w, attn_l, attn_r, w_l, w_r);
  L384_bprep<<<256, 256, 0, stream>>>(fc_w, Bt);
  L384_wprep<<<128, 256, 0, stream>>>(W_w, Wt);
  L384_xprep<<<12500, 256, 0, stream>>>(h_dst_item, Xi);
  L384_xprep<<<12500, 256, 0, stream>>>(h_dst_user, Xu);
  L384_av<<<12500, 256, 0, stream>>>(h_src_user, w_l, el_u);
  L384_av<<<12500, 256, 0, stream>>>(h_src_item, w_l, el_i);
  L384_av<<<12500, 256, 0, stream>>>(h_dst_user, w_r, er_u);
  L384_av<<<12500, 256, 0, stream>>>(h_dst_item, w_r, er_i);

  // phase A: u2i (src=user, dst=item) -> z_item (second half of out)
  L384_zero<<<196, 256, 0, stream>>>(cur, NN);
  L384_hist<<<1954, 256, 0, stream>>>(u2i_dst, cur);
  L384_scan1<<<49, 256, 0, stream>>>(cur, indptr, bsum);
  L384_scan2<<<1, 1, 0, stream>>>(bsum, 49, indptr);
  L384_scan3<<<196, 256, 0, stream>>>(indptr, bsum, cur);
  L384_fill<<<1954, 256, 0, stream>>>(u2i_src, u2i_dst, cur, csr);
  L384_sort<<<196, 256, 0, stream>>>(indptr, csr);
  L384_gemm<<<3125, 256, 0, stream>>>(h_src_user, Bt, fs, NN);
  L384_agg<<<12500, 256, 0, stream>>>(indptr, csr, el_u, er_i, fs, gat_bias, Xi);
  L384_headm<<<3125, 256, 0, stream>>>(Xi, Wt, W_b, out + (size_t)NN * 128);

  // phase B: i2u (src=item, dst=user) -> z_user (first half of out)
  L384_zero<<<196, 256, 0, stream>>>(cur, NN);
  L384_hist<<<1954, 256, 0, stream>>>(i2u_dst, cur);
  L384_scan1<<<49, 256, 0, stream>>>(cur, indptr, bsum);
  L384_scan2<<<1, 1, 0, stream>>>(bsum, 49, indptr);
  L384_scan3<<<196, 256, 0, stream>>>(indptr, bsum, cur);
  L384_fill<<<1954, 256, 0, stream>>>(i2u_src, i2u_dst, cur, csr);
  L384_sort<<<196, 256, 0, stream>>>(indptr, csr);
  L384_gemm<<<3125, 256, 0, stream>>>(h_src_item, Bt, fs, NN);
  L384_agg<<<12500, 256, 0, stream>>>(indptr, csr, el_i, er_u, fs, gat_bias, Xu);
  L384_headm<<<3125, 256, 0, stream>>>(Xu, Wt, W_b, out);
}

// Round 24
// 694.571 us; speedup vs baseline: 2.4402x; 1.0450x over previous
//
#include <hip/hip_runtime.h>

#define NN 50000
#define EE 500000

typedef unsigned short u16;
typedef unsigned int u32;

typedef __attribute__((ext_vector_type(8))) __bf16 bf16x8;
typedef __attribute__((ext_vector_type(4))) float f32x4;

__device__ __forceinline__ float4 ld4(const float* p) { return *(const float4*)p; }

// round-to-nearest-even f32 -> bf16 bits (internal storage / MFMA inputs)
__device__ __forceinline__ u16 f2bf(float f) {
  u32 u = __float_as_uint(f);
  u += 0x7FFFu + ((u >> 16) & 1u);
  return (u16)(u >> 16);
}

// w_r[k][h] (f32, for fused xprep) ; wlB[h][k] bf16 padded to 16 rows (MFMA B-frag)
__global__ void L384_wred(const float* fc_w, const float* attn_l, const float* attn_r,
                          float* w_r, u16* wlB) {
  int k = threadIdx.x;
  for (int h = 0; h < 4; ++h) {
    float sl = 0.f, sr = 0.f;
    for (int d = 0; d < 64; ++d) {
      float f = fc_w[k * 256 + h * 64 + d];
      sl += f * attn_l[h * 64 + d];
      sr += f * attn_r[h * 64 + d];
    }
    w_r[k * 4 + h] = sr;
    wlB[h * 256 + k] = f2bf(sl);
  }
  for (int h = 4; h < 16; ++h) wlB[h * 256 + k] = 0;
}

// Bt[n][k] = bf16(fc_w[k][n])
__global__ void L384_bprep(const float* B, u16* Bt) {
  int n = blockIdx.x;
  int k = threadIdx.x;
  Bt[n * 256 + k] = f2bf(B[(size_t)k * 256 + n]);
}

// Wt[n][k] = bf16(Ww[k][n]), n in [0,128), k in [0,320)
__global__ void L384_wprep(const float* Ww, u16* Wt) {
  int n = blockIdx.x;
  for (int k = threadIdx.x; k < 320; k += 256)
    Wt[(size_t)n * 320 + k] = f2bf(Ww[(size_t)k * 128 + n]);
}

// fused: X[n][64+c] = bf16(hdst[n][c])  AND  er[n][h] = dot(hdst[n], w_r[:,h])
__global__ void L384_xprep(const float* hdst, const float* wr_, u16* X, float* er) {
  const int row = blockIdx.x * 4 + (threadIdx.x >> 6);
  const int lane = threadIdx.x & 63;
  if (row >= NN) return;
  float4 xv = ld4(hdst + (size_t)row * 256 + lane * 4);
  u32 p01 = (u32)f2bf(xv.x) | ((u32)f2bf(xv.y) << 16);
  u32 p23 = (u32)f2bf(xv.z) | ((u32)f2bf(xv.w) << 16);
  *(uint2*)(X + (size_t)row * 320 + 64 + lane * 4) = make_uint2(p01, p23);
  const float* wr = wr_ + lane * 16;
  float4 w0 = ld4(wr), w1 = ld4(wr + 4), w2 = ld4(wr + 8), w3 = ld4(wr + 12);
  float a0 = xv.x * w0.x + xv.y * w1.x + xv.z * w2.x + xv.w * w3.x;
  float a1 = xv.x * w0.y + xv.y * w1.y + xv.z * w2.y + xv.w * w3.y;
  float a2 = xv.x * w0.z + xv.y * w1.z + xv.z * w2.z + xv.w * w3.z;
  float a3 = xv.x * w0.w + xv.y * w1.w + xv.z * w2.w + xv.w * w3.w;
  for (int off = 32; off; off >>= 1) {
    a0 += __shfl_xor(a0, off);
    a1 += __shfl_xor(a1, off);
    a2 += __shfl_xor(a2, off);
    a3 += __shfl_xor(a3, off);
  }
  if (lane == 0) {
    float* op = er + (size_t)row * 4;
    op[0] = a0; op[1] = a1; op[2] = a2; op[3] = a3;
  }
}

// fs = bf16(A) @ fc_w via MFMA; fused el = A @ w_l on wave 0.
// Block: 64 rows (4 row-groups x 16), 4 waves x 64-col strips (4 tiles each).
__global__ void L384_gemm(const float* A, const u16* Bt, const u16* wlB,
                          u16* C, float* el, int M) {
  const int t = threadIdx.x;
  const int w = t >> 6;
  const int l = t & 63;
  const int row0 = blockIdx.x * 64;
  const int lr = l & 15;
  const int kg = l >> 4;
  f32x4 acc[4][4];
  f32x4 eacc[4];
#pragma unroll
  for (int rg = 0; rg < 4; ++rg) {
    eacc[rg] = (f32x4){0.f, 0.f, 0.f, 0.f};
#pragma unroll
    for (int ct = 0; ct < 4; ++ct) acc[rg][ct] = (f32x4){0.f, 0.f, 0.f, 0.f};
  }
  const float* arow[4];
#pragma unroll
  for (int rg = 0; rg < 4; ++rg) {
    int r = row0 + rg * 16 + lr;
    if (r >= M) r = M - 1;
    arow[rg] = A + (size_t)r * 256 + kg * 8;
  }
  const u16* bb = Bt + (size_t)(w * 64 + lr) * 256 + kg * 8;
  const u16* wl = wlB + lr * 256 + kg * 8;
  for (int k0 = 0; k0 < 256; k0 += 32) {
    union { bf16x8 v; u16 s[8]; } af[4];
#pragma unroll
    for (int rg = 0; rg < 4; ++rg) {
      float4 a0 = ld4(arow[rg] + k0);
      float4 a1 = ld4(arow[rg] + k0 + 4);
      af[rg].s[0] = f2bf(a0.x); af[rg].s[1] = f2bf(a0.y);
      af[rg].s[2] = f2bf(a0.z); af[rg].s[3] = f2bf(a0.w);
      af[rg].s[4] = f2bf(a1.x); af[rg].s[5] = f2bf(a1.y);
      af[rg].s[6] = f2bf(a1.z); af[rg].s[7] = f2bf(a1.w);
    }
    union { bf16x8 v; uint4 q; } b[4], wf;
#pragma unroll
    for (int ct = 0; ct < 4; ++ct)
      b[ct].q = *(const uint4*)(bb + ct * 16 * 256 + k0);
    wf.q = *(const uint4*)(wl + k0);
#pragma unroll
    for (int rg = 0; rg < 4; ++rg) {
#pragma unroll
      for (int ct = 0; ct < 4; ++ct)
        acc[rg][ct] = __builtin_amdgcn_mfma_f32_16x16x32_bf16(af[rg].v, b[ct].v,
                                                              acc[rg][ct], 0, 0, 0);
      if (w == 0)
        eacc[rg] = __builtin_amdgcn_mfma_f32_16x16x32_bf16(af[rg].v, wf.v,
                                                           eacc[rg], 0, 0, 0);
    }
  }
#pragma unroll
  for (int rg = 0; rg < 4; ++rg) {
#pragma unroll
    for (int r = 0; r < 4; ++r) {
      int grow = row0 + rg * 16 + kg * 4 + r;
      if (grow < M) {
        u16* cp = C + (size_t)grow * 256 + w * 64 + lr;
        cp[0] = f2bf(acc[rg][0][r]);
        cp[16] = f2bf(acc[rg][1][r]);
        cp[32] = f2bf(acc[rg][2][r]);
        cp[48] = f2bf(acc[rg][3][r]);
      }
    }
    if (w == 0 && lr < 4) {
#pragma unroll
      for (int r = 0; r < 4; ++r) {
        int grow = row0 + rg * 16 + kg * 4 + r;
        if (grow < M) el[(size_t)grow * 4 + lr] = eacc[rg][r];
      }
    }
  }
}

__global__ void L384_zero(int* p, int n) {
  int i = blockIdx.x * 256 + threadIdx.x;
  if (i < n) p[i] = 0;
}
__global__ void L384_hist(const int* dst, int* cnt) {
  int e = blockIdx.x * 256 + threadIdx.x;
  if (e < EE) {
    int d = dst[e];
    d = ((unsigned)d < NN) ? d : 0;
    atomicAdd(&cnt[d], 1);
  }
}
__global__ void L384_scan1(const int* cnt, int* part, int* bsum) {
  __shared__ int sh[256];
  const int t = threadIdx.x;
  const int base = blockIdx.x * 1024 + t * 4;
  int v0 = (base + 0 < NN) ? cnt[base + 0] : 0;
  int v1 = (base + 1 < NN) ? cnt[base + 1] : 0;
  int v2 = (base + 2 < NN) ? cnt[base + 2] : 0;
  int v3 = (base + 3 < NN) ? cnt[base + 3] : 0;
  int s0 = v0, s1 = s0 + v1, s2 = s1 + v2, s3 = s2 + v3;
  sh[t] = s3;
  __syncthreads();
  for (int off = 1; off < 256; off <<= 1) {
    int x = (t >= off) ? sh[t - off] : 0;
    __syncthreads();
    sh[t] += x;
    __syncthreads();
  }
  int excl = (t > 0) ? sh[t - 1] : 0;
  if (base + 0 < NN) part[base + 0] = excl;
  if (base + 1 < NN) part[base + 1] = excl + s0;
  if (base + 2 < NN) part[base + 2] = excl + s1;
  if (base + 3 < NN) part[base + 3] = excl + s2;
  if (t == 255) bsum[blockIdx.x] = sh[255];
}
__global__ void L384_scan2(int* bsum, int nb, int* indptr) {
  if (threadIdx.x == 0 && blockIdx.x == 0) {
    int acc = 0;
    for (int i = 0; i < nb; ++i) {
      int c = bsum[i];
      bsum[i] = acc;
      acc += c;
    }
    indptr[NN] = acc;
  }
}
__global__ void L384_scan3(int* indptr, const int* bsum, int* cur) {
  int i = blockIdx.x * 256 + threadIdx.x;
  if (i < NN) {
    int v = indptr[i] + bsum[i >> 10];
    indptr[i] = v;
    cur[i] = v;
  }
}
__global__ void L384_fill(const int* src, const int* dst, int* cur, int* csr) {
  int e = blockIdx.x * 256 + threadIdx.x;
  if (e < EE) {
    int d = dst[e];
    d = ((unsigned)d < NN) ? d : 0;
    int pos = atomicAdd(&cur[d], 1);
    if ((unsigned)pos < EE) csr[pos] = src[e];
  }
}
// per-node insertion sort of CSR segment -> deterministic summation order
__global__ void L384_sort(const int* indptr, int* csr) {
  int i = blockIdx.x * 256 + threadIdx.x;
  if (i >= NN) return;
  int p0 = indptr[i], p1 = indptr[i + 1];
  for (int a = p0 + 1; a < p1; ++a) {
    int v = csr[a];
    int b = a - 1;
    while (b >= p0 && csr[b] > v) {
      csr[b + 1] = csr[b];
      --b;
    }
    csr[b + 1] = v;
  }
}

// one wave per dst node: edge softmax + weighted sum of fs[src];
// head-mean (+bias) written as bf16 into X[:,0:64]
__global__ void L384_agg(const int* indptr, const int* csr, const float* el,
                         const float* er, const u16* fs, const float* bias,
                         u16* X) {
  const int wid = blockIdx.x * 4 + (threadIdx.x >> 6);
  const int lane = threadIdx.x & 63;
  if (wid >= NN) return;
  const int p0 = indptr[wid];
  const int deg = indptr[wid + 1] - p0;
  const int h = lane >> 4;
  const int c = lane & 15;
  const float* erp = er + (size_t)wid * 4;
  float er0 = erp[0], er1 = erp[1], er2 = erp[2], er3 = erp[3];

  float m0 = -1e30f, m1 = -1e30f, m2 = -1e30f, m3 = -1e30f;
  for (int i = lane; i < deg; i += 64) {
    int s = csr[p0 + i];
    s = ((unsigned)s < NN) ? s : 0;
    const float* ep = el + (size_t)s * 4;
    float e0 = ep[0] + er0; e0 = (e0 >= 0.f) ? e0 : 0.2f * e0; m0 = fmaxf(m0, e0);
    float e1 = ep[1] + er1; e1 = (e1 >= 0.f) ? e1 : 0.2f * e1; m1 = fmaxf(m1, e1);
    float e2 = ep[2] + er2; e2 = (e2 >= 0.f) ? e2 : 0.2f * e2; m2 = fmaxf(m2, e2);
    float e3 = ep[3] + er3; e3 = (e3 >= 0.f) ? e3 : 0.2f * e3; m3 = fmaxf(m3, e3);
  }
  for (int off = 32; off; off >>= 1) {
    m0 = fmaxf(m0, __shfl_xor(m0, off));
    m1 = fmaxf(m1, __shfl_xor(m1, off));
    m2 = fmaxf(m2, __shfl_xor(m2, off));
    m3 = fmaxf(m3, __shfl_xor(m3, off));
  }
  float mh = (h == 0) ? m0 : (h == 1) ? m1 : (h == 2) ? m2 : m3;
  float erh = (h == 0) ? er0 : (h == 1) ? er1 : (h == 2) ? er2 : er3;

  float den = 0.f;
  float ax = 0.f, ay = 0.f, az = 0.f, aw = 0.f;
  for (int i = 0; i < deg; ++i) {
    int s = csr[p0 + i];
    s = ((unsigned)s < NN) ? s : 0;
    float e = el[(size_t)s * 4 + h] + erh;
    e = (e >= 0.f) ? e : 0.2f * e;
    float ex = __expf(e - mh);
    den += ex;
    uint2 q = *(const uint2*)(fs + (size_t)s * 256 + lane * 4);
    float fx = __uint_as_float(q.x << 16);
    float fy = __uint_as_float(q.x & 0xffff0000u);
    float fz = __uint_as_float(q.y << 16);
    float fw = __uint_as_float(q.y & 0xffff0000u);
    ax += ex * fx; ay += ex * fy; az += ex * fz; aw += ex * fw;
  }
  const float* bp = bias + lane * 4;
  float inv = (deg > 0) ? 1.f / den : 0.f;
  float ox = ax * inv + bp[0];
  float oy = ay * inv + bp[1];
  float oz = az * inv + bp[2];
  float ow = aw * inv + bp[3];
  for (int off = 16; off <= 32; off <<= 1) {
    ox += __shfl_xor(ox, off);
    oy += __shfl_xor(oy, off);
    oz += __shfl_xor(oz, off);
    ow += __shfl_xor(ow, off);
  }
  if (h == 0) {
    u32 p01 = (u32)f2bf(ox * 0.25f) | ((u32)f2bf(oy * 0.25f) << 16);
    u32 p23 = (u32)f2bf(oz * 0.25f) | ((u32)f2bf(ow * 0.25f) << 16);
    *(uint2*)(X + (size_t)wid * 320 + 4 * c) = make_uint2(p01, p23);
  }
}

// head via MFMA: out[r][c] = l2norm_row(relu(X @ Ww + Wb)); X bf16 [NN][320].
__global__ void L384_headm(const u16* X, const u16* Wt, const float* Wb, float* out) {
  __shared__ float red[4][16];
  const int t = threadIdx.x;
  const int w = t >> 6;
  const int l = t & 63;
  const int row0 = blockIdx.x * 16;
  const int lr = l & 15;
  const int kg = l >> 4;
  f32x4 acc0 = {0.f, 0.f, 0.f, 0.f};
  f32x4 acc1 = {0.f, 0.f, 0.f, 0.f};
  const u16* arow = X + (size_t)(row0 + lr) * 320 + kg * 8;
  const u16* b0row = Wt + (size_t)(w * 32 + lr) * 320 + kg * 8;
  const u16* b1row = Wt + (size_t)(w * 32 + 16 + lr) * 320 + kg * 8;
  for (int k0 = 0; k0 < 320; k0 += 32) {
    union { bf16x8 v; uint4 q; } af, b0, b1;
    af.q = *(const uint4*)(arow + k0);
    b0.q = *(const uint4*)(b0row + k0);
    b1.q = *(const uint4*)(b1row + k0);
    acc0 = __builtin_amdgcn_mfma_f32_16x16x32_bf16(af.v, b0.v, acc0, 0, 0, 0);
    acc1 = __builtin_amdgcn_mfma_f32_16x16x32_bf16(af.v, b1.v, acc1, 0, 0, 0);
  }
  const int col0 = w * 32 + lr;
  const int col1 = col0 + 16;
  float wb0 = Wb[col0], wb1 = Wb[col1];
  float z0[4], z1[4], pssq[4];
#pragma unroll
  for (int r = 0; r < 4; ++r) {
    z0[r] = fmaxf(acc0[r] + wb0, 0.f);
    z1[r] = fmaxf(acc1[r] + wb1, 0.f);
    pssq[r] = z0[r] * z0[r] + z1[r] * z1[r];
  }
#pragma unroll
  for (int off = 8; off; off >>= 1) {
#pragma unroll
    for (int r = 0; r < 4; ++r) pssq[r] += __shfl_xor(pssq[r], off);
  }
  if (lr == 0) {
#pragma unroll
    for (int r = 0; r < 4; ++r) red[w][kg * 4 + r] = pssq[r];
  }
  __syncthreads();
#pragma unroll
  for (int r = 0; r < 4; ++r) {
    int row = kg * 4 + r;
    float ssq = red[0][row] + red[1][row] + red[2][row] + red[3][row];
    float inv = (ssq > 0.f) ? rsqrtf(ssq) : 0.f;
    float* op = out + (size_t)(row0 + row) * 128;
    op[col0] = z0[r] * inv;
    op[col1] = z1[r] * inv;
  }
}

extern "C" void kernel_launch(void* const* d_in, const int* in_sizes, int n_in,
                              void* d_out, int out_size, void* d_ws, size_t ws_size,
                              hipStream_t stream) {
  (void)in_sizes; (void)n_in; (void)out_size; (void)ws_size;
  const float* h_src_user = (const float*)d_in[0];
  const float* h_src_item = (const float*)d_in[1];
  const float* h_dst_user = (const float*)d_in[2];
  const float* h_dst_item = (const float*)d_in[3];
  const int* u2i_src = (const int*)d_in[4];
  const int* u2i_dst = (const int*)d_in[5];
  const int* i2u_src = (const int*)d_in[6];
  const int* i2u_dst = (const int*)d_in[7];
  const float* fc_w = (const float*)d_in[8];
  const float* attn_l = (const float*)d_in[9];
  const float* attn_r = (const float*)d_in[10];
  const float* gat_bias = (const float*)d_in[11];
  const float* W_w = (const float*)d_in[12];
  const float* W_b = (const float*)d_in[13];
  float* out = (float*)d_out;  // f32 output

  float* el_u = (float*)d_ws;                   // NN*4
  float* el_i = el_u + (size_t)NN * 4;
  float* er_u = el_i + (size_t)NN * 4;
  float* er_i = er_u + (size_t)NN * 4;
  float* w_r = er_i + (size_t)NN * 4;           // 1024
  u16* wlB = (u16*)(w_r + 1024);                // 16*256 bf16
  u16* fs = wlB + 16 * 256;                     // NN*256 bf16
  u16* Xi = fs + (size_t)NN * 256;              // NN*320 bf16
  u16* Xu = Xi + (size_t)NN * 320;              // NN*320 bf16
  u16* Bt = Xu + (size_t)NN * 320;              // 256*256 bf16
  u16* Wt = Bt + 256 * 256;                     // 128*320 bf16
  int* indptr = (int*)(Wt + 128 * 320);         // NN+1 (+pad)
  int* cur = indptr + (NN + 4);                 // NN
  int* csr = cur + NN;                          // EE
  int* bsum = csr + EE;                         // 64

  // shared precompute
  L384_wred<<<1, 256, 0, stream>>>(fc_w, attn_l, attn_r, w_r, wlB);
  L384_bprep<<<256, 256, 0, stream>>>(fc_w, Bt);
  L384_wprep<<<128, 256, 0, stream>>>(W_w, Wt);
  L384_xprep<<<12500, 256, 0, stream>>>(h_dst_item, w_r, Xi, er_i);
  L384_xprep<<<12500, 256, 0, stream>>>(h_dst_user, w_r, Xu, er_u);

  // phase A: u2i (src=user, dst=item) -> z_item (second half of out)
  L384_zero<<<196, 256, 0, stream>>>(cur, NN);
  L384_hist<<<1954, 256, 0, stream>>>(u2i_dst, cur);
  L384_scan1<<<49, 256, 0, stream>>>(cur, indptr, bsum);
  L384_scan2<<<1, 1, 0, stream>>>(bsum, 49, indptr);
  L384_scan3<<<196, 256, 0, stream>>>(indptr, bsum, cur);
  L384_fill<<<1954, 256, 0, stream>>>(u2i_src, u2i_dst, cur, csr);
  L384_sort<<<196, 256, 0, stream>>>(indptr, csr);
  L384_gemm<<<782, 256, 0, stream>>>(h_src_user, Bt, wlB, fs, el_u, NN);
  L384_agg<<<12500, 256, 0, stream>>>(indptr, csr, el_u, er_i, fs, gat_bias, Xi);
  L384_headm<<<3125, 256, 0, stream>>>(Xi, Wt, W_b, out + (size_t)NN * 128);

  // phase B: i2u (src=item, dst=user) -> z_user (first half of out)
  L384_zero<<<196, 256, 0, stream>>>(cur, NN);
  L384_hist<<<1954, 256, 0, stream>>>(i2u_dst, cur);
  L384_scan1<<<49, 256, 0, stream>>>(cur, indptr, bsum);
  L384_scan2<<<1, 1, 0, stream>>>(bsum, 49, indptr);
  L384_scan3<<<196, 256, 0, stream>>>(indptr, bsum, cur);
  L384_fill<<<1954, 256, 0, stream>>>(i2u_src, i2u_dst, cur, csr);
  L384_sort<<<196, 256, 0, stream>>>(indptr, csr);
  L384_gemm<<<782, 256, 0, stream>>>(h_src_item, Bt, wlB, fs, el_i, NN);
  L384_agg<<<12500, 256, 0, stream>>>(indptr, csr, el_i, er_u, fs, gat_bias, Xu);
  L384_headm<<<3125, 256, 0, stream>>>(Xu, Wt, W_b, out);
}

// Round 25
// 616.437 us; speedup vs baseline: 2.7495x; 1.1268x over previous
//
#include <hip/hip_runtime.h>

#define NN 50000
#define N2 100000
#define EE 500000
#define E2 1000000

typedef unsigned short u16;
typedef unsigned int u32;

typedef __attribute__((ext_vector_type(8))) __bf16 bf16x8;
typedef __attribute__((ext_vector_type(4))) float f32x4;

__device__ __forceinline__ float4 ld4(const float* p) { return *(const float4*)p; }

// round-to-nearest-even f32 -> bf16 bits
__device__ __forceinline__ u16 f2bf(float f) {
  u32 u = __float_as_uint(f);
  u += 0x7FFFu + ((u >> 16) & 1u);
  return (u16)(u >> 16);
}

// w_r[k][h] (f32) ; wlB[h][k] bf16 padded to 16 rows (MFMA B-frag)
__global__ void L384_wred(const float* fc_w, const float* attn_l, const float* attn_r,
                          float* w_r, u16* wlB) {
  int k = threadIdx.x;
  for (int h = 0; h < 4; ++h) {
    float sl = 0.f, sr = 0.f;
    for (int d = 0; d < 64; ++d) {
      float f = fc_w[k * 256 + h * 64 + d];
      sl += f * attn_l[h * 64 + d];
      sr += f * attn_r[h * 64 + d];
    }
    w_r[k * 4 + h] = sr;
    wlB[h * 256 + k] = f2bf(sl);
  }
  for (int h = 4; h < 16; ++h) wlB[h * 256 + k] = 0;
}

// Bt[n][k] = bf16(fc_w[k][n])
__global__ void L384_bprep(const float* B, u16* Bt) {
  int n = blockIdx.x;
  int k = threadIdx.x;
  Bt[n * 256 + k] = f2bf(B[(size_t)k * 256 + n]);
}

// Wt[n][k] = bf16(Ww[k][n])
__global__ void L384_wprep(const float* Ww, u16* Wt) {
  int n = blockIdx.x;
  for (int k = threadIdx.x; k < 320; k += 256)
    Wt[(size_t)n * 320 + k] = f2bf(Ww[(size_t)k * 128 + n]);
}

// merged xprep over 2NN rows: rows <NN from h_dst_user, else h_dst_item.
// X[n][64+c] = bf16(hdst[n][c]); er[n][h] = dot(hdst row, w_r[:,h])
__global__ void L384_xprep(const float* hd_user, const float* hd_item,
                           const float* wr_, u16* X, float* er) {
  const int row = blockIdx.x * 4 + (threadIdx.x >> 6);
  const int lane = threadIdx.x & 63;
  if (row >= N2) return;
  const float* src = (row < NN) ? (hd_user + (size_t)row * 256)
                                : (hd_item + (size_t)(row - NN) * 256);
  float4 xv = ld4(src + lane * 4);
  u32 p01 = (u32)f2bf(xv.x) | ((u32)f2bf(xv.y) << 16);
  u32 p23 = (u32)f2bf(xv.z) | ((u32)f2bf(xv.w) << 16);
  *(uint2*)(X + (size_t)row * 320 + 64 + lane * 4) = make_uint2(p01, p23);
  const float* wr = wr_ + lane * 16;
  float4 w0 = ld4(wr), w1 = ld4(wr + 4), w2 = ld4(wr + 8), w3 = ld4(wr + 12);
  float a0 = xv.x * w0.x + xv.y * w1.x + xv.z * w2.x + xv.w * w3.x;
  float a1 = xv.x * w0.y + xv.y * w1.y + xv.z * w2.y + xv.w * w3.y;
  float a2 = xv.x * w0.z + xv.y * w1.z + xv.z * w2.z + xv.w * w3.z;
  float a3 = xv.x * w0.w + xv.y * w1.w + xv.z * w2.w + xv.w * w3.w;
  for (int off = 32; off; off >>= 1) {
    a0 += __shfl_xor(a0, off);
    a1 += __shfl_xor(a1, off);
    a2 += __shfl_xor(a2, off);
    a3 += __shfl_xor(a3, off);
  }
  if (lane == 0) {
    float* op = er + (size_t)row * 4;
    op[0] = a0; op[1] = a1; op[2] = a2; op[3] = a3;
  }
}

// merged gemm: blocks <782 -> h_src_user (fs/el rows 0..), else h_src_item (+NN).
// Block: 64 rows (4 rg x 16), 4 waves x 64-col strips; fused el on wave 0.
__global__ void L384_gemm(const float* Au, const float* Ai, const u16* Bt,
                          const u16* wlB, u16* C, float* el) {
  const int t = threadIdx.x;
  const int w = t >> 6;
  const int l = t & 63;
  const int half = (blockIdx.x >= 782) ? 1 : 0;
  const float* A = half ? Ai : Au;
  const int base = half * NN;
  const int row0 = (blockIdx.x - half * 782) * 64;
  const int lr = l & 15;
  const int kg = l >> 4;
  f32x4 acc[4][4];
  f32x4 eacc[4];
#pragma unroll
  for (int rg = 0; rg < 4; ++rg) {
    eacc[rg] = (f32x4){0.f, 0.f, 0.f, 0.f};
#pragma unroll
    for (int ct = 0; ct < 4; ++ct) acc[rg][ct] = (f32x4){0.f, 0.f, 0.f, 0.f};
  }
  const float* arow[4];
#pragma unroll
  for (int rg = 0; rg < 4; ++rg) {
    int r = row0 + rg * 16 + lr;
    if (r >= NN) r = NN - 1;
    arow[rg] = A + (size_t)r * 256 + kg * 8;
  }
  const u16* bb = Bt + (size_t)(w * 64 + lr) * 256 + kg * 8;
  const u16* wl = wlB + lr * 256 + kg * 8;
  for (int k0 = 0; k0 < 256; k0 += 32) {
    union { bf16x8 v; u16 s[8]; } af[4];
#pragma unroll
    for (int rg = 0; rg < 4; ++rg) {
      float4 a0 = ld4(arow[rg] + k0);
      float4 a1 = ld4(arow[rg] + k0 + 4);
      af[rg].s[0] = f2bf(a0.x); af[rg].s[1] = f2bf(a0.y);
      af[rg].s[2] = f2bf(a0.z); af[rg].s[3] = f2bf(a0.w);
      af[rg].s[4] = f2bf(a1.x); af[rg].s[5] = f2bf(a1.y);
      af[rg].s[6] = f2bf(a1.z); af[rg].s[7] = f2bf(a1.w);
    }
    union { bf16x8 v; uint4 q; } b[4], wf;
#pragma unroll
    for (int ct = 0; ct < 4; ++ct)
      b[ct].q = *(const uint4*)(bb + ct * 16 * 256 + k0);
    wf.q = *(const uint4*)(wl + k0);
#pragma unroll
    for (int rg = 0; rg < 4; ++rg) {
#pragma unroll
      for (int ct = 0; ct < 4; ++ct)
        acc[rg][ct] = __builtin_amdgcn_mfma_f32_16x16x32_bf16(af[rg].v, b[ct].v,
                                                              acc[rg][ct], 0, 0, 0);
      if (w == 0)
        eacc[rg] = __builtin_amdgcn_mfma_f32_16x16x32_bf16(af[rg].v, wf.v,
                                                           eacc[rg], 0, 0, 0);
    }
  }
#pragma unroll
  for (int rg = 0; rg < 4; ++rg) {
#pragma unroll
    for (int r = 0; r < 4; ++r) {
      int grow = row0 + rg * 16 + kg * 4 + r;
      if (grow < NN) {
        u16* cp = C + (size_t)(base + grow) * 256 + w * 64 + lr;
        cp[0] = f2bf(acc[rg][0][r]);
        cp[16] = f2bf(acc[rg][1][r]);
        cp[32] = f2bf(acc[rg][2][r]);
        cp[48] = f2bf(acc[rg][3][r]);
      }
    }
    if (w == 0 && lr < 4) {
#pragma unroll
      for (int r = 0; r < 4; ++r) {
        int grow = row0 + rg * 16 + kg * 4 + r;
        if (grow < NN) el[(size_t)(base + grow) * 4 + lr] = eacc[rg][r];
      }
    }
  }
}

__global__ void L384_zero(int* p, int n) {
  int i = blockIdx.x * 256 + threadIdx.x;
  if (i < n) p[i] = 0;
}
// merged hist over 2EE edges: e<EE -> i2u (dst user), else u2i (dst item+NN)
__global__ void L384_hist(const int* i2u_dst, const int* u2i_dst, int* cnt) {
  int e = blockIdx.x * 256 + threadIdx.x;
  if (e < EE) {
    int d = i2u_dst[e];
    d = ((unsigned)d < NN) ? d : 0;
    atomicAdd(&cnt[d], 1);
  } else if (e < E2) {
    int d = u2i_dst[e - EE];
    d = ((unsigned)d < NN) ? d : 0;
    atomicAdd(&cnt[NN + d], 1);
  }
}
__global__ void L384_scan1(const int* cnt, int* part, int* bsum, int n) {
  __shared__ int sh[256];
  const int t = threadIdx.x;
  const int base = blockIdx.x * 1024 + t * 4;
  int v0 = (base + 0 < n) ? cnt[base + 0] : 0;
  int v1 = (base + 1 < n) ? cnt[base + 1] : 0;
  int v2 = (base + 2 < n) ? cnt[base + 2] : 0;
  int v3 = (base + 3 < n) ? cnt[base + 3] : 0;
  int s0 = v0, s1 = s0 + v1, s2 = s1 + v2, s3 = s2 + v3;
  sh[t] = s3;
  __syncthreads();
  for (int off = 1; off < 256; off <<= 1) {
    int x = (t >= off) ? sh[t - off] : 0;
    __syncthreads();
    sh[t] += x;
    __syncthreads();
  }
  int excl = (t > 0) ? sh[t - 1] : 0;
  if (base + 0 < n) part[base + 0] = excl;
  if (base + 1 < n) part[base + 1] = excl + s0;
  if (base + 2 < n) part[base + 2] = excl + s1;
  if (base + 3 < n) part[base + 3] = excl + s2;
  if (t == 255) bsum[blockIdx.x] = sh[255];
}
__global__ void L384_scan2(int* bsum, int nb, int* indptr, int n) {
  if (threadIdx.x == 0 && blockIdx.x == 0) {
    int acc = 0;
    for (int i = 0; i < nb; ++i) {
      int c = bsum[i];
      bsum[i] = acc;
      acc += c;
    }
    indptr[n] = acc;
  }
}
__global__ void L384_scan3(int* indptr, const int* bsum, int* cur, int n) {
  int i = blockIdx.x * 256 + threadIdx.x;
  if (i < n) {
    int v = indptr[i] + bsum[i >> 10];
    indptr[i] = v;
    cur[i] = v;
  }
}
// merged fill: csr value = merged src id (i2u src -> +NN; u2i src -> +0)
__global__ void L384_fill(const int* i2u_src, const int* i2u_dst,
                          const int* u2i_src, const int* u2i_dst,
                          int* cur, int* csr) {
  int e = blockIdx.x * 256 + threadIdx.x;
  if (e < EE) {
    int d = i2u_dst[e];
    d = ((unsigned)d < NN) ? d : 0;
    int s = i2u_src[e];
    s = ((unsigned)s < NN) ? s : 0;
    int pos = atomicAdd(&cur[d], 1);
    if ((unsigned)pos < E2) csr[pos] = NN + s;
  } else if (e < E2) {
    int d = u2i_dst[e - EE];
    d = ((unsigned)d < NN) ? d : 0;
    int s = u2i_src[e - EE];
    s = ((unsigned)s < NN) ? s : 0;
    int pos = atomicAdd(&cur[NN + d], 1);
    if ((unsigned)pos < E2) csr[pos] = s;
  }
}
// per-node insertion sort -> deterministic summation order
__global__ void L384_sort(const int* indptr, int* csr, int n) {
  int i = blockIdx.x * 256 + threadIdx.x;
  if (i >= n) return;
  int p0 = indptr[i], p1 = indptr[i + 1];
  for (int a = p0 + 1; a < p1; ++a) {
    int v = csr[a];
    int b = a - 1;
    while (b >= p0 && csr[b] > v) {
      csr[b + 1] = csr[b];
      --b;
    }
    csr[b + 1] = v;
  }
}

// merged agg over 2NN dst nodes; writes bf16 head-mean(+bias) into X[:,0:64]
__global__ void L384_agg(const int* indptr, const int* csr, const float* el,
                         const float* er, const u16* fs, const float* bias,
                         u16* X) {
  const int wid = blockIdx.x * 4 + (threadIdx.x >> 6);
  const int lane = threadIdx.x & 63;
  if (wid >= N2) return;
  const int p0 = indptr[wid];
  const int deg = indptr[wid + 1] - p0;
  const int h = lane >> 4;
  const int c = lane & 15;
  const float* erp = er + (size_t)wid * 4;
  float er0 = erp[0], er1 = erp[1], er2 = erp[2], er3 = erp[3];

  float m0 = -1e30f, m1 = -1e30f, m2 = -1e30f, m3 = -1e30f;
  for (int i = lane; i < deg; i += 64) {
    int s = csr[p0 + i];
    s = ((unsigned)s < N2) ? s : 0;
    const float* ep = el + (size_t)s * 4;
    float e0 = ep[0] + er0; e0 = (e0 >= 0.f) ? e0 : 0.2f * e0; m0 = fmaxf(m0, e0);
    float e1 = ep[1] + er1; e1 = (e1 >= 0.f) ? e1 : 0.2f * e1; m1 = fmaxf(m1, e1);
    float e2 = ep[2] + er2; e2 = (e2 >= 0.f) ? e2 : 0.2f * e2; m2 = fmaxf(m2, e2);
    float e3 = ep[3] + er3; e3 = (e3 >= 0.f) ? e3 : 0.2f * e3; m3 = fmaxf(m3, e3);
  }
  for (int off = 32; off; off >>= 1) {
    m0 = fmaxf(m0, __shfl_xor(m0, off));
    m1 = fmaxf(m1, __shfl_xor(m1, off));
    m2 = fmaxf(m2, __shfl_xor(m2, off));
    m3 = fmaxf(m3, __shfl_xor(m3, off));
  }
  float mh = (h == 0) ? m0 : (h == 1) ? m1 : (h == 2) ? m2 : m3;
  float erh = (h == 0) ? er0 : (h == 1) ? er1 : (h == 2) ? er2 : er3;

  float den = 0.f;
  float ax = 0.f, ay = 0.f, az = 0.f, aw = 0.f;
  for (int i = 0; i < deg; ++i) {
    int s = csr[p0 + i];
    s = ((unsigned)s < N2) ? s : 0;
    float e = el[(size_t)s * 4 + h] + erh;
    e = (e >= 0.f) ? e : 0.2f * e;
    float ex = __expf(e - mh);
    den += ex;
    uint2 q = *(const uint2*)(fs + (size_t)s * 256 + lane * 4);
    float fx = __uint_as_float(q.x << 16);
    float fy = __uint_as_float(q.x & 0xffff0000u);
    float fz = __uint_as_float(q.y << 16);
    float fw = __uint_as_float(q.y & 0xffff0000u);
    ax += ex * fx; ay += ex * fy; az += ex * fz; aw += ex * fw;
  }
  const float* bp = bias + lane * 4;
  float inv = (deg > 0) ? 1.f / den : 0.f;
  float ox = ax * inv + bp[0];
  float oy = ay * inv + bp[1];
  float oz = az * inv + bp[2];
  float ow = aw * inv + bp[3];
  for (int off = 16; off <= 32; off <<= 1) {
    ox += __shfl_xor(ox, off);
    oy += __shfl_xor(oy, off);
    oz += __shfl_xor(oz, off);
    ow += __shfl_xor(ow, off);
  }
  if (h == 0) {
    u32 p01 = (u32)f2bf(ox * 0.25f) | ((u32)f2bf(oy * 0.25f) << 16);
    u32 p23 = (u32)f2bf(oz * 0.25f) | ((u32)f2bf(ow * 0.25f) << 16);
    *(uint2*)(X + (size_t)wid * 320 + 4 * c) = make_uint2(p01, p23);
  }
}

// head via MFMA over merged X[2NN][320]; out rows 0..2NN-1 = [z_user; z_item]
__global__ void L384_headm(const u16* X, const u16* Wt, const float* Wb, float* out) {
  __shared__ float red[4][16];
  const int t = threadIdx.x;
  const int w = t >> 6;
  const int l = t & 63;
  const int row0 = blockIdx.x * 16;
  const int lr = l & 15;
  const int kg = l >> 4;
  f32x4 acc0 = {0.f, 0.f, 0.f, 0.f};
  f32x4 acc1 = {0.f, 0.f, 0.f, 0.f};
  const u16* arow = X + (size_t)(row0 + lr) * 320 + kg * 8;
  const u16* b0row = Wt + (size_t)(w * 32 + lr) * 320 + kg * 8;
  const u16* b1row = Wt + (size_t)(w * 32 + 16 + lr) * 320 + kg * 8;
  for (int k0 = 0; k0 < 320; k0 += 32) {
    union { bf16x8 v; uint4 q; } af, b0, b1;
    af.q = *(const uint4*)(arow + k0);
    b0.q = *(const uint4*)(b0row + k0);
    b1.q = *(const uint4*)(b1row + k0);
    acc0 = __builtin_amdgcn_mfma_f32_16x16x32_bf16(af.v, b0.v, acc0, 0, 0, 0);
    acc1 = __builtin_amdgcn_mfma_f32_16x16x32_bf16(af.v, b1.v, acc1, 0, 0, 0);
  }
  const int col0 = w * 32 + lr;
  const int col1 = col0 + 16;
  float wb0 = Wb[col0], wb1 = Wb[col1];
  float z0[4], z1[4], pssq[4];
#pragma unroll
  for (int r = 0; r < 4; ++r) {
    z0[r] = fmaxf(acc0[r] + wb0, 0.f);
    z1[r] = fmaxf(acc1[r] + wb1, 0.f);
    pssq[r] = z0[r] * z0[r] + z1[r] * z1[r];
  }
#pragma unroll
  for (int off = 8; off; off >>= 1) {
#pragma unroll
    for (int r = 0; r < 4; ++r) pssq[r] += __shfl_xor(pssq[r], off);
  }
  if (lr == 0) {
#pragma unroll
    for (int r = 0; r < 4; ++r) red[w][kg * 4 + r] = pssq[r];
  }
  __syncthreads();
#pragma unroll
  for (int r = 0; r < 4; ++r) {
    int row = kg * 4 + r;
    float ssq = red[0][row] + red[1][row] + red[2][row] + red[3][row];
    float inv = (ssq > 0.f) ? rsqrtf(ssq) : 0.f;
    float* op = out + (size_t)(row0 + row) * 128;
    op[col0] = z0[r] * inv;
    op[col1] = z1[r] * inv;
  }
}

extern "C" void kernel_launch(void* const* d_in, const int* in_sizes, int n_in,
                              void* d_out, int out_size, void* d_ws, size_t ws_size,
                              hipStream_t stream) {
  (void)in_sizes; (void)n_in; (void)out_size; (void)ws_size;
  const float* h_src_user = (const float*)d_in[0];
  const float* h_src_item = (const float*)d_in[1];
  const float* h_dst_user = (const float*)d_in[2];
  const float* h_dst_item = (const float*)d_in[3];
  const int* u2i_src = (const int*)d_in[4];
  const int* u2i_dst = (const int*)d_in[5];
  const int* i2u_src = (const int*)d_in[6];
  const int* i2u_dst = (const int*)d_in[7];
  const float* fc_w = (const float*)d_in[8];
  const float* attn_l = (const float*)d_in[9];
  const float* attn_r = (const float*)d_in[10];
  const float* gat_bias = (const float*)d_in[11];
  const float* W_w = (const float*)d_in[12];
  const float* W_b = (const float*)d_in[13];
  float* out = (float*)d_out;  // f32 [2NN][128] = [z_user; z_item]

  float* el = (float*)d_ws;                     // N2*4
  float* er = el + (size_t)N2 * 4;              // N2*4
  float* w_r = er + (size_t)N2 * 4;             // 1024
  u16* wlB = (u16*)(w_r + 1024);                // 16*256
  u16* fs = wlB + 16 * 256;                     // N2*256 bf16 (user rows 0.., item +NN)
  u16* X = fs + (size_t)N2 * 256;               // N2*320 bf16
  u16* Bt = X + (size_t)N2 * 320;               // 256*256
  u16* Wt = Bt + 256 * 256;                     // 128*320
  int* indptr = (int*)(Wt + 128 * 320);         // N2+1 (+pad)
  int* cur = indptr + (N2 + 4);                 // N2
  int* csr = cur + N2;                          // E2
  int* bsum = csr + E2;                         // 128

  // shared precompute
  L384_wred<<<1, 256, 0, stream>>>(fc_w, attn_l, attn_r, w_r, wlB);
  L384_bprep<<<256, 256, 0, stream>>>(fc_w, Bt);
  L384_wprep<<<128, 256, 0, stream>>>(W_w, Wt);
  L384_xprep<<<25000, 256, 0, stream>>>(h_dst_user, h_dst_item, w_r, X, er);

  // merged CSR build (2NN nodes, 2EE edges)
  L384_zero<<<391, 256, 0, stream>>>(cur, N2);
  L384_hist<<<3907, 256, 0, stream>>>(i2u_dst, u2i_dst, cur);
  L384_scan1<<<98, 256, 0, stream>>>(cur, indptr, bsum, N2);
  L384_scan2<<<1, 1, 0, stream>>>(bsum, 98, indptr, N2);
  L384_scan3<<<391, 256, 0, stream>>>(indptr, bsum, cur, N2);
  L384_fill<<<3907, 256, 0, stream>>>(i2u_src, i2u_dst, u2i_src, u2i_dst, cur, csr);
  L384_sort<<<391, 256, 0, stream>>>(indptr, csr, N2);

  // merged compute
  L384_gemm<<<1564, 256, 0, stream>>>(h_src_user, h_src_item, Bt, wlB, fs, el);
  L384_agg<<<25000, 256, 0, stream>>>(indptr, csr, el, er, fs, gat_bias, X);
  L384_headm<<<6250, 256, 0, stream>>>(X, Wt, W_b, out);
}

// Round 26
// 570.830 us; speedup vs baseline: 2.9692x; 1.0799x over previous
//
#include <hip/hip_runtime.h>

#define NN 50000
#define N2 100000
#define EE 500000
#define E2 1000000

typedef unsigned short u16;
typedef unsigned int u32;

typedef __attribute__((ext_vector_type(8))) __bf16 bf16x8;
typedef __attribute__((ext_vector_type(4))) float f32x4;

__device__ __forceinline__ float4 ld4(const float* p) { return *(const float4*)p; }

// round-to-nearest-even f32 -> bf16 bits
__device__ __forceinline__ u16 f2bf(float f) {
  u32 u = __float_as_uint(f);
  u += 0x7FFFu + ((u >> 16) & 1u);
  return (u16)(u >> 16);
}

// w_r[k][h] (f32) ; wlB[h][k] bf16 padded to 16 rows (MFMA B-frag)
__global__ void L384_wred(const float* fc_w, const float* attn_l, const float* attn_r,
                          float* w_r, u16* wlB) {
  int k = threadIdx.x;
  for (int h = 0; h < 4; ++h) {
    float sl = 0.f, sr = 0.f;
    for (int d = 0; d < 64; ++d) {
      float f = fc_w[k * 256 + h * 64 + d];
      sl += f * attn_l[h * 64 + d];
      sr += f * attn_r[h * 64 + d];
    }
    w_r[k * 4 + h] = sr;
    wlB[h * 256 + k] = f2bf(sl);
  }
  for (int h = 4; h < 16; ++h) wlB[h * 256 + k] = 0;
}

// Bt[n][k] = bf16(fc_w[k][n])
__global__ void L384_bprep(const float* B, u16* Bt) {
  int n = blockIdx.x;
  int k = threadIdx.x;
  Bt[n * 256 + k] = f2bf(B[(size_t)k * 256 + n]);
}

// Wt[n][k] = bf16(Ww[k][n])
__global__ void L384_wprep(const float* Ww, u16* Wt) {
  int n = blockIdx.x;
  for (int k = threadIdx.x; k < 320; k += 256)
    Wt[(size_t)n * 320 + k] = f2bf(Ww[(size_t)k * 128 + n]);
}

// merged xprep over 2NN rows: rows <NN from h_dst_user, else h_dst_item.
__global__ void L384_xprep(const float* hd_user, const float* hd_item,
                           const float* wr_, u16* X, float* er) {
  const int row = blockIdx.x * 4 + (threadIdx.x >> 6);
  const int lane = threadIdx.x & 63;
  if (row >= N2) return;
  const float* src = (row < NN) ? (hd_user + (size_t)row * 256)
                                : (hd_item + (size_t)(row - NN) * 256);
  float4 xv = ld4(src + lane * 4);
  u32 p01 = (u32)f2bf(xv.x) | ((u32)f2bf(xv.y) << 16);
  u32 p23 = (u32)f2bf(xv.z) | ((u32)f2bf(xv.w) << 16);
  *(uint2*)(X + (size_t)row * 320 + 64 + lane * 4) = make_uint2(p01, p23);
  const float* wr = wr_ + lane * 16;
  float4 w0 = ld4(wr), w1 = ld4(wr + 4), w2 = ld4(wr + 8), w3 = ld4(wr + 12);
  float a0 = xv.x * w0.x + xv.y * w1.x + xv.z * w2.x + xv.w * w3.x;
  float a1 = xv.x * w0.y + xv.y * w1.y + xv.z * w2.y + xv.w * w3.y;
  float a2 = xv.x * w0.z + xv.y * w1.z + xv.z * w2.z + xv.w * w3.z;
  float a3 = xv.x * w0.w + xv.y * w1.w + xv.z * w2.w + xv.w * w3.w;
  for (int off = 32; off; off >>= 1) {
    a0 += __shfl_xor(a0, off);
    a1 += __shfl_xor(a1, off);
    a2 += __shfl_xor(a2, off);
    a3 += __shfl_xor(a3, off);
  }
  if (lane == 0) {
    float* op = er + (size_t)row * 4;
    op[0] = a0; op[1] = a1; op[2] = a2; op[3] = a3;
  }
}

// merged gemm: blocks <1563 -> h_src_user, else h_src_item (+NN).
// Block: 32 rows (2 rg x 16), 4 waves x 64-col strips; fused el on wave 0.
// C-write staged through LDS for coalesced uint4 stores.
__global__ void L384_gemm(const float* Au, const float* Ai, const u16* Bt,
                          const u16* wlB, u16* C, float* el) {
  __shared__ u16 cs[32][264];  // pad 264: <=4-way ds_write conflict, 16B-aligned rows
  const int t = threadIdx.x;
  const int w = t >> 6;
  const int l = t & 63;
  const int half = (blockIdx.x >= 1563) ? 1 : 0;
  const float* A = half ? Ai : Au;
  const int base = half * NN;
  const int row0 = (blockIdx.x - half * 1563) * 32;
  const int lr = l & 15;
  const int kg = l >> 4;
  f32x4 acc[2][4];
  f32x4 eacc[2];
#pragma unroll
  for (int rg = 0; rg < 2; ++rg) {
    eacc[rg] = (f32x4){0.f, 0.f, 0.f, 0.f};
#pragma unroll
    for (int ct = 0; ct < 4; ++ct) acc[rg][ct] = (f32x4){0.f, 0.f, 0.f, 0.f};
  }
  const float* arow[2];
#pragma unroll
  for (int rg = 0; rg < 2; ++rg) {
    int r = row0 + rg * 16 + lr;
    if (r >= NN) r = NN - 1;
    arow[rg] = A + (size_t)r * 256 + kg * 8;
  }
  const u16* bb = Bt + (size_t)(w * 64 + lr) * 256 + kg * 8;
  const u16* wl = wlB + lr * 256 + kg * 8;
  for (int k0 = 0; k0 < 256; k0 += 32) {
    union { bf16x8 v; u16 s[8]; } af[2];
#pragma unroll
    for (int rg = 0; rg < 2; ++rg) {
      float4 a0 = ld4(arow[rg] + k0);
      float4 a1 = ld4(arow[rg] + k0 + 4);
      af[rg].s[0] = f2bf(a0.x); af[rg].s[1] = f2bf(a0.y);
      af[rg].s[2] = f2bf(a0.z); af[rg].s[3] = f2bf(a0.w);
      af[rg].s[4] = f2bf(a1.x); af[rg].s[5] = f2bf(a1.y);
      af[rg].s[6] = f2bf(a1.z); af[rg].s[7] = f2bf(a1.w);
    }
    union { bf16x8 v; uint4 q; } b[4], wf;
#pragma unroll
    for (int ct = 0; ct < 4; ++ct)
      b[ct].q = *(const uint4*)(bb + ct * 16 * 256 + k0);
    wf.q = *(const uint4*)(wl + k0);
#pragma unroll
    for (int rg = 0; rg < 2; ++rg) {
#pragma unroll
      for (int ct = 0; ct < 4; ++ct)
        acc[rg][ct] = __builtin_amdgcn_mfma_f32_16x16x32_bf16(af[rg].v, b[ct].v,
                                                              acc[rg][ct], 0, 0, 0);
      if (w == 0)
        eacc[rg] = __builtin_amdgcn_mfma_f32_16x16x32_bf16(af[rg].v, wf.v,
                                                           eacc[rg], 0, 0, 0);
    }
  }
  // stage D-fragments into LDS
#pragma unroll
  for (int rg = 0; rg < 2; ++rg)
#pragma unroll
    for (int ct = 0; ct < 4; ++ct)
#pragma unroll
      for (int r = 0; r < 4; ++r)
        cs[rg * 16 + kg * 4 + r][w * 64 + ct * 16 + lr] = f2bf(acc[rg][ct][r]);
  // el (tiny, direct)
#pragma unroll
  for (int rg = 0; rg < 2; ++rg) {
    if (w == 0 && lr < 4) {
#pragma unroll
      for (int r = 0; r < 4; ++r) {
        int grow = row0 + rg * 16 + kg * 4 + r;
        if (grow < NN) el[(size_t)(base + grow) * 4 + lr] = eacc[rg][r];
      }
    }
  }
  __syncthreads();
  // coalesced write: 8 threads/row, 4 uint4 each
  const int row = t >> 3;
  const int c0 = (t & 7) * 32;
  const int grow = row0 + row;
  if (grow < NN) {
    const uint4* src = (const uint4*)&cs[row][c0];
    uint4* dst = (uint4*)(C + (size_t)(base + grow) * 256 + c0);
    dst[0] = src[0];
    dst[1] = src[1];
    dst[2] = src[2];
    dst[3] = src[3];
  }
}

__global__ void L384_zero(int* p, int n) {
  int i = blockIdx.x * 256 + threadIdx.x;
  if (i < n) p[i] = 0;
}
// merged hist over 2EE edges
__global__ void L384_hist(const int* i2u_dst, const int* u2i_dst, int* cnt) {
  int e = blockIdx.x * 256 + threadIdx.x;
  if (e < EE) {
    int d = i2u_dst[e];
    d = ((unsigned)d < NN) ? d : 0;
    atomicAdd(&cnt[d], 1);
  } else if (e < E2) {
    int d = u2i_dst[e - EE];
    d = ((unsigned)d < NN) ? d : 0;
    atomicAdd(&cnt[NN + d], 1);
  }
}
__global__ void L384_scan1(const int* cnt, int* part, int* bsum, int n) {
  __shared__ int sh[256];
  const int t = threadIdx.x;
  const int base = blockIdx.x * 1024 + t * 4;
  int v0 = (base + 0 < n) ? cnt[base + 0] : 0;
  int v1 = (base + 1 < n) ? cnt[base + 1] : 0;
  int v2 = (base + 2 < n) ? cnt[base + 2] : 0;
  int v3 = (base + 3 < n) ? cnt[base + 3] : 0;
  int s0 = v0, s1 = s0 + v1, s2 = s1 + v2, s3 = s2 + v3;
  sh[t] = s3;
  __syncthreads();
  for (int off = 1; off < 256; off <<= 1) {
    int x = (t >= off) ? sh[t - off] : 0;
    __syncthreads();
    sh[t] += x;
    __syncthreads();
  }
  int excl = (t > 0) ? sh[t - 1] : 0;
  if (base + 0 < n) part[base + 0] = excl;
  if (base + 1 < n) part[base + 1] = excl + s0;
  if (base + 2 < n) part[base + 2] = excl + s1;
  if (base + 3 < n) part[base + 3] = excl + s2;
  if (t == 255) bsum[blockIdx.x] = sh[255];
}
__global__ void L384_scan2(int* bsum, int nb, int* indptr, int n) {
  if (threadIdx.x == 0 && blockIdx.x == 0) {
    int acc = 0;
    for (int i = 0; i < nb; ++i) {
      int c = bsum[i];
      bsum[i] = acc;
      acc += c;
    }
    indptr[n] = acc;
  }
}
__global__ void L384_scan3(int* indptr, const int* bsum, int* cur, int n) {
  int i = blockIdx.x * 256 + threadIdx.x;
  if (i < n) {
    int v = indptr[i] + bsum[i >> 10];
    indptr[i] = v;
    cur[i] = v;
  }
}
__global__ void L384_fill(const int* i2u_src, const int* i2u_dst,
                          const int* u2i_src, const int* u2i_dst,
                          int* cur, int* csr) {
  int e = blockIdx.x * 256 + threadIdx.x;
  if (e < EE) {
    int d = i2u_dst[e];
    d = ((unsigned)d < NN) ? d : 0;
    int s = i2u_src[e];
    s = ((unsigned)s < NN) ? s : 0;
    int pos = atomicAdd(&cur[d], 1);
    if ((unsigned)pos < E2) csr[pos] = NN + s;
  } else if (e < E2) {
    int d = u2i_dst[e - EE];
    d = ((unsigned)d < NN) ? d : 0;
    int s = u2i_src[e - EE];
    s = ((unsigned)s < NN) ? s : 0;
    int pos = atomicAdd(&cur[NN + d], 1);
    if ((unsigned)pos < E2) csr[pos] = s;
  }
}
__global__ void L384_sort(const int* indptr, int* csr, int n) {
  int i = blockIdx.x * 256 + threadIdx.x;
  if (i >= n) return;
  int p0 = indptr[i], p1 = indptr[i + 1];
  for (int a = p0 + 1; a < p1; ++a) {
    int v = csr[a];
    int b = a - 1;
    while (b >= p0 && csr[b] > v) {
      csr[b + 1] = csr[b];
      --b;
    }
    csr[b + 1] = v;
  }
}

// merged agg over 2NN dst nodes; writes bf16 head-mean(+bias) into X[:,0:64]
__global__ void L384_agg(const int* indptr, const int* csr, const float* el,
                         const float* er, const u16* fs, const float* bias,
                         u16* X) {
  const int wid = blockIdx.x * 4 + (threadIdx.x >> 6);
  const int lane = threadIdx.x & 63;
  if (wid >= N2) return;
  const int p0 = indptr[wid];
  const int deg = indptr[wid + 1] - p0;
  const int h = lane >> 4;
  const int c = lane & 15;
  const float* erp = er + (size_t)wid * 4;
  float er0 = erp[0], er1 = erp[1], er2 = erp[2], er3 = erp[3];

  float m0 = -1e30f, m1 = -1e30f, m2 = -1e30f, m3 = -1e30f;
  for (int i = lane; i < deg; i += 64) {
    int s = csr[p0 + i];
    s = ((unsigned)s < N2) ? s : 0;
    const float* ep = el + (size_t)s * 4;
    float e0 = ep[0] + er0; e0 = (e0 >= 0.f) ? e0 : 0.2f * e0; m0 = fmaxf(m0, e0);
    float e1 = ep[1] + er1; e1 = (e1 >= 0.f) ? e1 : 0.2f * e1; m1 = fmaxf(m1, e1);
    float e2 = ep[2] + er2; e2 = (e2 >= 0.f) ? e2 : 0.2f * e2; m2 = fmaxf(m2, e2);
    float e3 = ep[3] + er3; e3 = (e3 >= 0.f) ? e3 : 0.2f * e3; m3 = fmaxf(m3, e3);
  }
  for (int off = 32; off; off >>= 1) {
    m0 = fmaxf(m0, __shfl_xor(m0, off));
    m1 = fmaxf(m1, __shfl_xor(m1, off));
    m2 = fmaxf(m2, __shfl_xor(m2, off));
    m3 = fmaxf(m3, __shfl_xor(m3, off));
  }
  float mh = (h == 0) ? m0 : (h == 1) ? m1 : (h == 2) ? m2 : m3;
  float erh = (h == 0) ? er0 : (h == 1) ? er1 : (h == 2) ? er2 : er3;

  float den = 0.f;
  float ax = 0.f, ay = 0.f, az = 0.f, aw = 0.f;
  for (int i = 0; i < deg; ++i) {
    int s = csr[p0 + i];
    s = ((unsigned)s < N2) ? s : 0;
    float e = el[(size_t)s * 4 + h] + erh;
    e = (e >= 0.f) ? e : 0.2f * e;
    float ex = __expf(e - mh);
    den += ex;
    uint2 q = *(const uint2*)(fs + (size_t)s * 256 + lane * 4);
    float fx = __uint_as_float(q.x << 16);
    float fy = __uint_as_float(q.x & 0xffff0000u);
    float fz = __uint_as_float(q.y << 16);
    float fw = __uint_as_float(q.y & 0xffff0000u);
    ax += ex * fx; ay += ex * fy; az += ex * fz; aw += ex * fw;
  }
  const float* bp = bias + lane * 4;
  float inv = (deg > 0) ? 1.f / den : 0.f;
  float ox = ax * inv + bp[0];
  float oy = ay * inv + bp[1];
  float oz = az * inv + bp[2];
  float ow = aw * inv + bp[3];
  for (int off = 16; off <= 32; off <<= 1) {
    ox += __shfl_xor(ox, off);
    oy += __shfl_xor(oy, off);
    oz += __shfl_xor(oz, off);
    ow += __shfl_xor(ow, off);
  }
  if (h == 0) {
    u32 p01 = (u32)f2bf(ox * 0.25f) | ((u32)f2bf(oy * 0.25f) << 16);
    u32 p23 = (u32)f2bf(oz * 0.25f) | ((u32)f2bf(ow * 0.25f) << 16);
    *(uint2*)(X + (size_t)wid * 320 + 4 * c) = make_uint2(p01, p23);
  }
}

// head via MFMA over merged X[2NN][320]; out rows = [z_user; z_item]
__global__ void L384_headm(const u16* X, const u16* Wt, const float* Wb, float* out) {
  __shared__ float red[4][16];
  const int t = threadIdx.x;
  const int w = t >> 6;
  const int l = t & 63;
  const int row0 = blockIdx.x * 16;
  const int lr = l & 15;
  const int kg = l >> 4;
  f32x4 acc0 = {0.f, 0.f, 0.f, 0.f};
  f32x4 acc1 = {0.f, 0.f, 0.f, 0.f};
  const u16* arow = X + (size_t)(row0 + lr) * 320 + kg * 8;
  const u16* b0row = Wt + (size_t)(w * 32 + lr) * 320 + kg * 8;
  const u16* b1row = Wt + (size_t)(w * 32 + 16 + lr) * 320 + kg * 8;
  for (int k0 = 0; k0 < 320; k0 += 32) {
    union { bf16x8 v; uint4 q; } af, b0, b1;
    af.q = *(const uint4*)(arow + k0);
    b0.q = *(const uint4*)(b0row + k0);
    b1.q = *(const uint4*)(b1row + k0);
    acc0 = __builtin_amdgcn_mfma_f32_16x16x32_bf16(af.v, b0.v, acc0, 0, 0, 0);
    acc1 = __builtin_amdgcn_mfma_f32_16x16x32_bf16(af.v, b1.v, acc1, 0, 0, 0);
  }
  const int col0 = w * 32 + lr;
  const int col1 = col0 + 16;
  float wb0 = Wb[col0], wb1 = Wb[col1];
  float z0[4], z1[4], pssq[4];
#pragma unroll
  for (int r = 0; r < 4; ++r) {
    z0[r] = fmaxf(acc0[r] + wb0, 0.f);
    z1[r] = fmaxf(acc1[r] + wb1, 0.f);
    pssq[r] = z0[r] * z0[r] + z1[r] * z1[r];
  }
#pragma unroll
  for (int off = 8; off; off >>= 1) {
#pragma unroll
    for (int r = 0; r < 4; ++r) pssq[r] += __shfl_xor(pssq[r], off);
  }
  if (lr == 0) {
#pragma unroll
    for (int r = 0; r < 4; ++r) red[w][kg * 4 + r] = pssq[r];
  }
  __syncthreads();
#pragma unroll
  for (int r = 0; r < 4; ++r) {
    int row = kg * 4 + r;
    float ssq = red[0][row] + red[1][row] + red[2][row] + red[3][row];
    float inv = (ssq > 0.f) ? rsqrtf(ssq) : 0.f;
    float* op = out + (size_t)(row0 + row) * 128;
    op[col0] = z0[r] * inv;
    op[col1] = z1[r] * inv;
  }
}

extern "C" void kernel_launch(void* const* d_in, const int* in_sizes, int n_in,
                              void* d_out, int out_size, void* d_ws, size_t ws_size,
                              hipStream_t stream) {
  (void)in_sizes; (void)n_in; (void)out_size; (void)ws_size;
  const float* h_src_user = (const float*)d_in[0];
  const float* h_src_item = (const float*)d_in[1];
  const float* h_dst_user = (const float*)d_in[2];
  const float* h_dst_item = (const float*)d_in[3];
  const int* u2i_src = (const int*)d_in[4];
  const int* u2i_dst = (const int*)d_in[5];
  const int* i2u_src = (const int*)d_in[6];
  const int* i2u_dst = (const int*)d_in[7];
  const float* fc_w = (const float*)d_in[8];
  const float* attn_l = (const float*)d_in[9];
  const float* attn_r = (const float*)d_in[10];
  const float* gat_bias = (const float*)d_in[11];
  const float* W_w = (const float*)d_in[12];
  const float* W_b = (const float*)d_in[13];
  float* out = (float*)d_out;  // f32 [2NN][128] = [z_user; z_item]

  float* el = (float*)d_ws;                     // N2*4
  float* er = el + (size_t)N2 * 4;              // N2*4
  float* w_r = er + (size_t)N2 * 4;             // 1024
  u16* wlB = (u16*)(w_r + 1024);                // 16*256
  u16* fs = wlB + 16 * 256;                     // N2*256 bf16
  u16* X = fs + (size_t)N2 * 256;               // N2*320 bf16
  u16* Bt = X + (size_t)N2 * 320;               // 256*256
  u16* Wt = Bt + 256 * 256;                     // 128*320
  int* indptr = (int*)(Wt + 128 * 320);         // N2+1 (+pad)
  int* cur = indptr + (N2 + 4);                 // N2
  int* csr = cur + N2;                          // E2
  int* bsum = csr + E2;                         // 128

  // shared precompute
  L384_wred<<<1, 256, 0, stream>>>(fc_w, attn_l, attn_r, w_r, wlB);
  L384_bprep<<<256, 256, 0, stream>>>(fc_w, Bt);
  L384_wprep<<<128, 256, 0, stream>>>(W_w, Wt);
  L384_xprep<<<25000, 256, 0, stream>>>(h_dst_user, h_dst_item, w_r, X, er);

  // merged CSR build (2NN nodes, 2EE edges)
  L384_zero<<<391, 256, 0, stream>>>(cur, N2);
  L384_hist<<<3907, 256, 0, stream>>>(i2u_dst, u2i_dst, cur);
  L384_scan1<<<98, 256, 0, stream>>>(cur, indptr, bsum, N2);
  L384_scan2<<<1, 1, 0, stream>>>(bsum, 98, indptr, N2);
  L384_scan3<<<391, 256, 0, stream>>>(indptr, bsum, cur, N2);
  L384_fill<<<3907, 256, 0, stream>>>(i2u_src, i2u_dst, u2i_src, u2i_dst, cur, csr);
  L384_sort<<<391, 256, 0, stream>>>(indptr, csr, N2);

  // merged compute
  L384_gemm<<<3126, 256, 0, stream>>>(h_src_user, h_src_item, Bt, wlB, fs, el);
  L384_agg<<<25000, 256, 0, stream>>>(indptr, csr, el, er, fs, gat_bias, X);
  L384_headm<<<6250, 256, 0, stream>>>(X, Wt, W_b, out);
}

// Round 27
// 522.719 us; speedup vs baseline: 3.2424x; 1.0920x over previous
//
#include <hip/hip_runtime.h>

#define NN 50000
#define N2 100000
#define EE 500000
#define E2 1000000

typedef unsigned short u16;
typedef unsigned int u32;

typedef __attribute__((ext_vector_type(8))) __bf16 bf16x8;
typedef __attribute__((ext_vector_type(4))) float f32x4;

__device__ __forceinline__ float4 ld4(const float* p) { return *(const float4*)p; }

// round-to-nearest-even f32 -> bf16 bits
__device__ __forceinline__ u16 f2bf(float f) {
  u32 u = __float_as_uint(f);
  u += 0x7FFFu + ((u >> 16) & 1u);
  return (u16)(u >> 16);
}

// w_r[k][h] (f32) ; wlB[h][k] bf16 padded to 16 rows (MFMA B-frag)
__global__ void L384_wred(const float* fc_w, const float* attn_l, const float* attn_r,
                          float* w_r, u16* wlB) {
  int k = threadIdx.x;
  for (int h = 0; h < 4; ++h) {
    float sl = 0.f, sr = 0.f;
    for (int d = 0; d < 64; ++d) {
      float f = fc_w[k * 256 + h * 64 + d];
      sl += f * attn_l[h * 64 + d];
      sr += f * attn_r[h * 64 + d];
    }
    w_r[k * 4 + h] = sr;
    wlB[h * 256 + k] = f2bf(sl);
  }
  for (int h = 4; h < 16; ++h) wlB[h * 256 + k] = 0;
}

// Bt[n][k] = bf16(fc_w[k][n])
__global__ void L384_bprep(const float* B, u16* Bt) {
  int n = blockIdx.x;
  int k = threadIdx.x;
  Bt[n * 256 + k] = f2bf(B[(size_t)k * 256 + n]);
}

// Wt[n][k] = bf16(Ww[k][n])
__global__ void L384_wprep(const float* Ww, u16* Wt) {
  int n = blockIdx.x;
  for (int k = threadIdx.x; k < 320; k += 256)
    Wt[(size_t)n * 320 + k] = f2bf(Ww[(size_t)k * 128 + n]);
}

// merged xprep over 2NN rows
__global__ void L384_xprep(const float* hd_user, const float* hd_item,
                           const float* wr_, u16* X, float* er) {
  const int row = blockIdx.x * 4 + (threadIdx.x >> 6);
  const int lane = threadIdx.x & 63;
  if (row >= N2) return;
  const float* src = (row < NN) ? (hd_user + (size_t)row * 256)
                                : (hd_item + (size_t)(row - NN) * 256);
  float4 xv = ld4(src + lane * 4);
  u32 p01 = (u32)f2bf(xv.x) | ((u32)f2bf(xv.y) << 16);
  u32 p23 = (u32)f2bf(xv.z) | ((u32)f2bf(xv.w) << 16);
  *(uint2*)(X + (size_t)row * 320 + 64 + lane * 4) = make_uint2(p01, p23);
  const float* wr = wr_ + lane * 16;
  float4 w0 = ld4(wr), w1 = ld4(wr + 4), w2 = ld4(wr + 8), w3 = ld4(wr + 12);
  float a0 = xv.x * w0.x + xv.y * w1.x + xv.z * w2.x + xv.w * w3.x;
  float a1 = xv.x * w0.y + xv.y * w1.y + xv.z * w2.y + xv.w * w3.y;
  float a2 = xv.x * w0.z + xv.y * w1.z + xv.z * w2.z + xv.w * w3.z;
  float a3 = xv.x * w0.w + xv.y * w1.w + xv.z * w2.w + xv.w * w3.w;
  for (int off = 32; off; off >>= 1) {
    a0 += __shfl_xor(a0, off);
    a1 += __shfl_xor(a1, off);
    a2 += __shfl_xor(a2, off);
    a3 += __shfl_xor(a3, off);
  }
  if (lane == 0) {
    float* op = er + (size_t)row * 4;
    op[0] = a0; op[1] = a1; op[2] = a2; op[3] = a3;
  }
}

// merged gemm (32 rows/block, LDS-staged C-write, fused el on wave 0)
__global__ void L384_gemm(const float* Au, const float* Ai, const u16* Bt,
                          const u16* wlB, u16* C, float* el) {
  __shared__ u16 cs[32][264];
  const int t = threadIdx.x;
  const int w = t >> 6;
  const int l = t & 63;
  const int half = (blockIdx.x >= 1563) ? 1 : 0;
  const float* A = half ? Ai : Au;
  const int base = half * NN;
  const int row0 = (blockIdx.x - half * 1563) * 32;
  const int lr = l & 15;
  const int kg = l >> 4;
  f32x4 acc[2][4];
  f32x4 eacc[2];
#pragma unroll
  for (int rg = 0; rg < 2; ++rg) {
    eacc[rg] = (f32x4){0.f, 0.f, 0.f, 0.f};
#pragma unroll
    for (int ct = 0; ct < 4; ++ct) acc[rg][ct] = (f32x4){0.f, 0.f, 0.f, 0.f};
  }
  const float* arow[2];
#pragma unroll
  for (int rg = 0; rg < 2; ++rg) {
    int r = row0 + rg * 16 + lr;
    if (r >= NN) r = NN - 1;
    arow[rg] = A + (size_t)r * 256 + kg * 8;
  }
  const u16* bb = Bt + (size_t)(w * 64 + lr) * 256 + kg * 8;
  const u16* wl = wlB + lr * 256 + kg * 8;
  for (int k0 = 0; k0 < 256; k0 += 32) {
    union { bf16x8 v; u16 s[8]; } af[2];
#pragma unroll
    for (int rg = 0; rg < 2; ++rg) {
      float4 a0 = ld4(arow[rg] + k0);
      float4 a1 = ld4(arow[rg] + k0 + 4);
      af[rg].s[0] = f2bf(a0.x); af[rg].s[1] = f2bf(a0.y);
      af[rg].s[2] = f2bf(a0.z); af[rg].s[3] = f2bf(a0.w);
      af[rg].s[4] = f2bf(a1.x); af[rg].s[5] = f2bf(a1.y);
      af[rg].s[6] = f2bf(a1.z); af[rg].s[7] = f2bf(a1.w);
    }
    union { bf16x8 v; uint4 q; } b[4], wf;
#pragma unroll
    for (int ct = 0; ct < 4; ++ct)
      b[ct].q = *(const uint4*)(bb + ct * 16 * 256 + k0);
    wf.q = *(const uint4*)(wl + k0);
#pragma unroll
    for (int rg = 0; rg < 2; ++rg) {
#pragma unroll
      for (int ct = 0; ct < 4; ++ct)
        acc[rg][ct] = __builtin_amdgcn_mfma_f32_16x16x32_bf16(af[rg].v, b[ct].v,
                                                              acc[rg][ct], 0, 0, 0);
      if (w == 0)
        eacc[rg] = __builtin_amdgcn_mfma_f32_16x16x32_bf16(af[rg].v, wf.v,
                                                           eacc[rg], 0, 0, 0);
    }
  }
#pragma unroll
  for (int rg = 0; rg < 2; ++rg)
#pragma unroll
    for (int ct = 0; ct < 4; ++ct)
#pragma unroll
      for (int r = 0; r < 4; ++r)
        cs[rg * 16 + kg * 4 + r][w * 64 + ct * 16 + lr] = f2bf(acc[rg][ct][r]);
#pragma unroll
  for (int rg = 0; rg < 2; ++rg) {
    if (w == 0 && lr < 4) {
#pragma unroll
      for (int r = 0; r < 4; ++r) {
        int grow = row0 + rg * 16 + kg * 4 + r;
        if (grow < NN) el[(size_t)(base + grow) * 4 + lr] = eacc[rg][r];
      }
    }
  }
  __syncthreads();
  const int row = t >> 3;
  const int c0 = (t & 7) * 32;
  const int grow = row0 + row;
  if (grow < NN) {
    const uint4* src = (const uint4*)&cs[row][c0];
    uint4* dst = (uint4*)(C + (size_t)(base + grow) * 256 + c0);
    dst[0] = src[0];
    dst[1] = src[1];
    dst[2] = src[2];
    dst[3] = src[3];
  }
}

__global__ void L384_zero(int* p, int n) {
  int i = blockIdx.x * 256 + threadIdx.x;
  if (i < n) p[i] = 0;
}
__global__ void L384_hist(const int* i2u_dst, const int* u2i_dst, int* cnt) {
  int e = blockIdx.x * 256 + threadIdx.x;
  if (e < EE) {
    int d = i2u_dst[e];
    d = ((unsigned)d < NN) ? d : 0;
    atomicAdd(&cnt[d], 1);
  } else if (e < E2) {
    int d = u2i_dst[e - EE];
    d = ((unsigned)d < NN) ? d : 0;
    atomicAdd(&cnt[NN + d], 1);
  }
}
__global__ void L384_scan1(const int* cnt, int* part, int* bsum, int n) {
  __shared__ int sh[256];
  const int t = threadIdx.x;
  const int base = blockIdx.x * 1024 + t * 4;
  int v0 = (base + 0 < n) ? cnt[base + 0] : 0;
  int v1 = (base + 1 < n) ? cnt[base + 1] : 0;
  int v2 = (base + 2 < n) ? cnt[base + 2] : 0;
  int v3 = (base + 3 < n) ? cnt[base + 3] : 0;
  int s0 = v0, s1 = s0 + v1, s2 = s1 + v2, s3 = s2 + v3;
  sh[t] = s3;
  __syncthreads();
  for (int off = 1; off < 256; off <<= 1) {
    int x = (t >= off) ? sh[t - off] : 0;
    __syncthreads();
    sh[t] += x;
    __syncthreads();
  }
  int excl = (t > 0) ? sh[t - 1] : 0;
  if (base + 0 < n) part[base + 0] = excl;
  if (base + 1 < n) part[base + 1] = excl + s0;
  if (base + 2 < n) part[base + 2] = excl + s1;
  if (base + 3 < n) part[base + 3] = excl + s2;
  if (t == 255) bsum[blockIdx.x] = sh[255];
}
__global__ void L384_scan2(int* bsum, int nb, int* indptr, int n) {
  if (threadIdx.x == 0 && blockIdx.x == 0) {
    int acc = 0;
    for (int i = 0; i < nb; ++i) {
      int c = bsum[i];
      bsum[i] = acc;
      acc += c;
    }
    indptr[n] = acc;
  }
}
__global__ void L384_scan3(int* indptr, const int* bsum, int* cur, int n) {
  int i = blockIdx.x * 256 + threadIdx.x;
  if (i < n) {
    int v = indptr[i] + bsum[i >> 10];
    indptr[i] = v;
    cur[i] = v;
  }
}
__global__ void L384_fill(const int* i2u_src, const int* i2u_dst,
                          const int* u2i_src, const int* u2i_dst,
                          int* cur, int* csr) {
  int e = blockIdx.x * 256 + threadIdx.x;
  if (e < EE) {
    int d = i2u_dst[e];
    d = ((unsigned)d < NN) ? d : 0;
    int s = i2u_src[e];
    s = ((unsigned)s < NN) ? s : 0;
    int pos = atomicAdd(&cur[d], 1);
    if ((unsigned)pos < E2) csr[pos] = NN + s;
  } else if (e < E2) {
    int d = u2i_dst[e - EE];
    d = ((unsigned)d < NN) ? d : 0;
    int s = u2i_src[e - EE];
    s = ((unsigned)s < NN) ? s : 0;
    int pos = atomicAdd(&cur[NN + d], 1);
    if ((unsigned)pos < E2) csr[pos] = s;
  }
}
__global__ void L384_sort(const int* indptr, int* csr, int n) {
  int i = blockIdx.x * 256 + threadIdx.x;
  if (i >= n) return;
  int p0 = indptr[i], p1 = indptr[i + 1];
  for (int a = p0 + 1; a < p1; ++a) {
    int v = csr[a];
    int b = a - 1;
    while (b >= p0 && csr[b] > v) {
      csr[b + 1] = csr[b];
      --b;
    }
    csr[b + 1] = v;
  }
}

// merged agg: single pass (no max subtraction — |e|<~4 so exp is safe in f32;
// alpha = exp(e)/sum exp(e) is mathematically identical to the max-shifted form).
// Edge loop unrolled x2 with strictly serial accumulation (deterministic).
__global__ void L384_agg(const int* indptr, const int* csr, const float* el,
                         const float* er, const u16* fs, const float* bias,
                         u16* X) {
  const int wid = blockIdx.x * 4 + (threadIdx.x >> 6);
  const int lane = threadIdx.x & 63;
  if (wid >= N2) return;
  const int p0 = indptr[wid];
  const int deg = indptr[wid + 1] - p0;
  const int h = lane >> 4;
  const int c = lane & 15;
  const float* erp = er + (size_t)wid * 4;
  float erh = erp[h];

  float den = 0.f;
  float ax = 0.f, ay = 0.f, az = 0.f, aw = 0.f;
  int i = 0;
  for (; i + 2 <= deg; i += 2) {
    int s0 = csr[p0 + i];
    int s1 = csr[p0 + i + 1];
    s0 = ((unsigned)s0 < N2) ? s0 : 0;
    s1 = ((unsigned)s1 < N2) ? s1 : 0;
    float e0 = el[(size_t)s0 * 4 + h] + erh;
    float e1 = el[(size_t)s1 * 4 + h] + erh;
    uint2 q0 = *(const uint2*)(fs + (size_t)s0 * 256 + lane * 4);
    uint2 q1 = *(const uint2*)(fs + (size_t)s1 * 256 + lane * 4);
    e0 = (e0 >= 0.f) ? e0 : 0.2f * e0;
    e1 = (e1 >= 0.f) ? e1 : 0.2f * e1;
    float ex0 = __expf(e0);
    float ex1 = __expf(e1);
    den += ex0;
    ax += ex0 * __uint_as_float(q0.x << 16);
    ay += ex0 * __uint_as_float(q0.x & 0xffff0000u);
    az += ex0 * __uint_as_float(q0.y << 16);
    aw += ex0 * __uint_as_float(q0.y & 0xffff0000u);
    den += ex1;
    ax += ex1 * __uint_as_float(q1.x << 16);
    ay += ex1 * __uint_as_float(q1.x & 0xffff0000u);
    az += ex1 * __uint_as_float(q1.y << 16);
    aw += ex1 * __uint_as_float(q1.y & 0xffff0000u);
  }
  if (i < deg) {
    int s0 = csr[p0 + i];
    s0 = ((unsigned)s0 < N2) ? s0 : 0;
    float e0 = el[(size_t)s0 * 4 + h] + erh;
    uint2 q0 = *(const uint2*)(fs + (size_t)s0 * 256 + lane * 4);
    e0 = (e0 >= 0.f) ? e0 : 0.2f * e0;
    float ex0 = __expf(e0);
    den += ex0;
    ax += ex0 * __uint_as_float(q0.x << 16);
    ay += ex0 * __uint_as_float(q0.x & 0xffff0000u);
    az += ex0 * __uint_as_float(q0.y << 16);
    aw += ex0 * __uint_as_float(q0.y & 0xffff0000u);
  }
  const float* bp = bias + lane * 4;
  float inv = (deg > 0) ? 1.f / den : 0.f;
  float ox = ax * inv + bp[0];
  float oy = ay * inv + bp[1];
  float oz = az * inv + bp[2];
  float ow = aw * inv + bp[3];
  for (int off = 16; off <= 32; off <<= 1) {
    ox += __shfl_xor(ox, off);
    oy += __shfl_xor(oy, off);
    oz += __shfl_xor(oz, off);
    ow += __shfl_xor(ow, off);
  }
  if (h == 0) {
    u32 p01 = (u32)f2bf(ox * 0.25f) | ((u32)f2bf(oy * 0.25f) << 16);
    u32 p23 = (u32)f2bf(oz * 0.25f) | ((u32)f2bf(ow * 0.25f) << 16);
    *(uint2*)(X + (size_t)wid * 320 + 4 * c) = make_uint2(p01, p23);
  }
}

// head via MFMA over merged X[2NN][320]; out rows = [z_user; z_item]
__global__ void L384_headm(const u16* X, const u16* Wt, const float* Wb, float* out) {
  __shared__ float red[4][16];
  const int t = threadIdx.x;
  const int w = t >> 6;
  const int l = t & 63;
  const int row0 = blockIdx.x * 16;
  const int lr = l & 15;
  const int kg = l >> 4;
  f32x4 acc0 = {0.f, 0.f, 0.f, 0.f};
  f32x4 acc1 = {0.f, 0.f, 0.f, 0.f};
  const u16* arow = X + (size_t)(row0 + lr) * 320 + kg * 8;
  const u16* b0row = Wt + (size_t)(w * 32 + lr) * 320 + kg * 8;
  const u16* b1row = Wt + (size_t)(w * 32 + 16 + lr) * 320 + kg * 8;
  for (int k0 = 0; k0 < 320; k0 += 32) {
    union { bf16x8 v; uint4 q; } af, b0, b1;
    af.q = *(const uint4*)(arow + k0);
    b0.q = *(const uint4*)(b0row + k0);
    b1.q = *(const uint4*)(b1row + k0);
    acc0 = __builtin_amdgcn_mfma_f32_16x16x32_bf16(af.v, b0.v, acc0, 0, 0, 0);
    acc1 = __builtin_amdgcn_mfma_f32_16x16x32_bf16(af.v, b1.v, acc1, 0, 0, 0);
  }
  const int col0 = w * 32 + lr;
  const int col1 = col0 + 16;
  float wb0 = Wb[col0], wb1 = Wb[col1];
  float z0[4], z1[4], pssq[4];
#pragma unroll
  for (int r = 0; r < 4; ++r) {
    z0[r] = fmaxf(acc0[r] + wb0, 0.f);
    z1[r] = fmaxf(acc1[r] + wb1, 0.f);
    pssq[r] = z0[r] * z0[r] + z1[r] * z1[r];
  }
#pragma unroll
  for (int off = 8; off; off >>= 1) {
#pragma unroll
    for (int r = 0; r < 4; ++r) pssq[r] += __shfl_xor(pssq[r], off);
  }
  if (lr == 0) {
#pragma unroll
    for (int r = 0; r < 4; ++r) red[w][kg * 4 + r] = pssq[r];
  }
  __syncthreads();
#pragma unroll
  for (int r = 0; r < 4; ++r) {
    int row = kg * 4 + r;
    float ssq = red[0][row] + red[1][row] + red[2][row] + red[3][row];
    float inv = (ssq > 0.f) ? rsqrtf(ssq) : 0.f;
    float* op = out + (size_t)(row0 + row) * 128;
    op[col0] = z0[r] * inv;
    op[col1] = z1[r] * inv;
  }
}

extern "C" void kernel_launch(void* const* d_in, const int* in_sizes, int n_in,
                              void* d_out, int out_size, void* d_ws, size_t ws_size,
                              hipStream_t stream) {
  (void)in_sizes; (void)n_in; (void)out_size; (void)ws_size;
  const float* h_src_user = (const float*)d_in[0];
  const float* h_src_item = (const float*)d_in[1];
  const float* h_dst_user = (const float*)d_in[2];
  const float* h_dst_item = (const float*)d_in[3];
  const int* u2i_src = (const int*)d_in[4];
  const int* u2i_dst = (const int*)d_in[5];
  const int* i2u_src = (const int*)d_in[6];
  const int* i2u_dst = (const int*)d_in[7];
  const float* fc_w = (const float*)d_in[8];
  const float* attn_l = (const float*)d_in[9];
  const float* attn_r = (const float*)d_in[10];
  const float* gat_bias = (const float*)d_in[11];
  const float* W_w = (const float*)d_in[12];
  const float* W_b = (const float*)d_in[13];
  float* out = (float*)d_out;  // f32 [2NN][128] = [z_user; z_item]

  float* el = (float*)d_ws;                     // N2*4
  float* er = el + (size_t)N2 * 4;              // N2*4
  float* w_r = er + (size_t)N2 * 4;             // 1024
  u16* wlB = (u16*)(w_r + 1024);                // 16*256
  u16* fs = wlB + 16 * 256;                     // N2*256 bf16
  u16* X = fs + (size_t)N2 * 256;               // N2*320 bf16
  u16* Bt = X + (size_t)N2 * 320;               // 256*256
  u16* Wt = Bt + 256 * 256;                     // 128*320
  int* indptr = (int*)(Wt + 128 * 320);         // N2+1 (+pad)
  int* cur = indptr + (N2 + 4);                 // N2
  int* csr = cur + N2;                          // E2
  int* bsum = csr + E2;                         // 128

  // shared precompute
  L384_wred<<<1, 256, 0, stream>>>(fc_w, attn_l, attn_r, w_r, wlB);
  L384_bprep<<<256, 256, 0, stream>>>(fc_w, Bt);
  L384_wprep<<<128, 256, 0, stream>>>(W_w, Wt);
  L384_xprep<<<25000, 256, 0, stream>>>(h_dst_user, h_dst_item, w_r, X, er);

  // merged CSR build (2NN nodes, 2EE edges)
  L384_zero<<<391, 256, 0, stream>>>(cur, N2);
  L384_hist<<<3907, 256, 0, stream>>>(i2u_dst, u2i_dst, cur);
  L384_scan1<<<98, 256, 0, stream>>>(cur, indptr, bsum, N2);
  L384_scan2<<<1, 1, 0, stream>>>(bsum, 98, indptr, N2);
  L384_scan3<<<391, 256, 0, stream>>>(indptr, bsum, cur, N2);
  L384_fill<<<3907, 256, 0, stream>>>(i2u_src, i2u_dst, u2i_src, u2i_dst, cur, csr);
  L384_sort<<<391, 256, 0, stream>>>(indptr, csr, N2);

  // merged compute
  L384_gemm<<<3126, 256, 0, stream>>>(h_src_user, h_src_item, Bt, wlB, fs, el);
  L384_agg<<<25000, 256, 0, stream>>>(indptr, csr, el, er, fs, gat_bias, X);
  L384_headm<<<6250, 256, 0, stream>>>(X, Wt, W_b, out);
}